// Round 6
// baseline (7336.769 us; speedup 1.0000x reference)
//
#include <hip/hip_runtime.h>
#include <float.h>
#include <math.h>

// ---------------------------------------------------------------------------
// CoKE model. Round 6: double-buffered LDS pipeline in mgemm + split-K for
// small-N GEMMs (partials reduced inside ln_k). XCD M-slice swizzle kept.
// B=32 SEQ=200 TOK=50 E=512 H=8 DH=64 NHID=2048 L=6 VOC=12525 TC_EMB=1024
// ---------------------------------------------------------------------------

#define B_   32
#define SEQ_ 200
#define TOK_ 50
#define E_   512
#define H_   8
#define DH_  64
#define NHID_ 2048
#define L_   6
#define VOC_ 12525
#define TCE_ 1024

typedef unsigned short ushort_t;
typedef __attribute__((ext_vector_type(8))) short bf16x8;
typedef __attribute__((ext_vector_type(4))) float f32x4;
typedef __attribute__((address_space(1))) const unsigned int GU32;
typedef __attribute__((address_space(3))) unsigned int LU32;

// ------------------------- helpers -----------------------------------------
__device__ __forceinline__ unsigned short f2bf(float x){
  unsigned u = __float_as_uint(x);
  unsigned r = u + 0x7fff + ((u >> 16) & 1);
  return (unsigned short)(r >> 16);
}
__device__ __forceinline__ float bf2f(unsigned short h){
  return __uint_as_float(((unsigned)h) << 16);
}

__device__ __forceinline__ float waveReduceSum(float v){
#pragma unroll
  for (int o = 32; o > 0; o >>= 1) v += __shfl_down(v, o, 64);
  return v;
}
__device__ __forceinline__ float waveReduceMax(float v){
#pragma unroll
  for (int o = 32; o > 0; o >>= 1) v = fmaxf(v, __shfl_down(v, o, 64));
  return v;
}
__device__ __forceinline__ float blockReduceSum256(float v, float* sm){
  v = waveReduceSum(v);
  int lane = threadIdx.x & 63, w = threadIdx.x >> 6;
  __syncthreads();
  if (lane == 0) sm[w] = v;
  __syncthreads();
  return sm[0] + sm[1] + sm[2] + sm[3];
}
__device__ __forceinline__ float blockReduceMax256(float v, float* sm){
  v = waveReduceMax(v);
  int lane = threadIdx.x & 63, w = threadIdx.x >> 6;
  __syncthreads();
  if (lane == 0) sm[w] = v;
  __syncthreads();
  return fmaxf(fmaxf(sm[0], sm[1]), fmaxf(sm[2], sm[3]));
}

// ------------------------- generic fp32 strided batched GEMM ---------------
__global__ __launch_bounds__(256) void gemm_k(
    const float* __restrict__ A, const float* __restrict__ B,
    const float* __restrict__ bias, const float* __restrict__ Res,
    float* __restrict__ C,
    int M, int N, int K,
    long long sAm, long long sAk, long long sBn, long long sBk,
    long long sCm, long long sRm,
    int Hd,
    long long bAb, long long bAh, long long bBb, long long bBh,
    long long bCb, long long bCh,
    float alpha, int epi)
{
  __shared__ float As[16][68];
  __shared__ float Bs[16][68];
  int z = blockIdx.z;
  int zb = z / Hd, zh = z - zb * Hd;
  A += (long long)zb * bAb + (long long)zh * bAh;
  B += (long long)zb * bBb + (long long)zh * bBh;
  C += (long long)zb * bCb + (long long)zh * bCh;
  int m0 = blockIdx.y * 64, n0 = blockIdx.x * 64;
  int tid = threadIdx.y * 16 + threadIdx.x;
  float acc[4][4] = {};
  for (int k0 = 0; k0 < K; k0 += 16) {
#pragma unroll
    for (int i = 0; i < 4; ++i) {
      int idx = tid + 256 * i;
      int kk = idx & 15, mm = idx >> 4;
      int m = m0 + mm, k = k0 + kk;
      As[kk][mm] = (m < M && k < K) ? A[(long long)m * sAm + (long long)k * sAk] : 0.f;
      int n = n0 + mm;
      Bs[kk][mm] = (n < N && k < K) ? B[(long long)n * sBn + (long long)k * sBk] : 0.f;
    }
    __syncthreads();
#pragma unroll
    for (int kk = 0; kk < 16; ++kk) {
      float a[4], b[4];
#pragma unroll
      for (int i = 0; i < 4; ++i) a[i] = As[kk][threadIdx.y * 4 + i];
#pragma unroll
      for (int j = 0; j < 4; ++j) b[j] = Bs[kk][threadIdx.x * 4 + j];
#pragma unroll
      for (int i = 0; i < 4; ++i)
#pragma unroll
        for (int j = 0; j < 4; ++j) acc[i][j] = fmaf(a[i], b[j], acc[i][j]);
    }
    __syncthreads();
  }
#pragma unroll
  for (int i = 0; i < 4; ++i) {
    int m = m0 + threadIdx.y * 4 + i;
    if (m >= M) continue;
#pragma unroll
    for (int j = 0; j < 4; ++j) {
      int n = n0 + threadIdx.x * 4 + j;
      if (n >= N) continue;
      float v = acc[i][j] * alpha;
      if (bias) v += bias[n];
      if (epi == 1) v = fmaxf(v, 0.f);
      else if (epi == 2) v = 0.5f * v * (1.f + erff(v * 0.70710678f));
      if (Res) v += Res[(long long)m * sRm + n];
      C[(long long)m * sCm + n] = v;
    }
  }
}

static inline void launch_gemm(hipStream_t st,
    const float* A, const float* B, const float* bias, const float* Res, float* C,
    int M, int N, int K,
    long long sAm, long long sAk, long long sBn, long long sBk,
    long long sCm, long long sRm,
    int nz, int Hd,
    long long bAb, long long bAh, long long bBb, long long bBh,
    long long bCb, long long bCh,
    float alpha, int epi)
{
  dim3 g((N + 63) / 64, (M + 63) / 64, nz), bl(16, 16);
  gemm_k<<<g, bl, 0, st>>>(A, B, bias, Res, C, M, N, K,
                           sAm, sAk, sBn, sBk, sCm, sRm, Hd,
                           bAb, bAh, bBb, bBh, bCb, bCh, alpha, epi);
}

// ------------------------- bf16x3 MFMA GEMM (XCD swizzle + dbuf + splitK) --
// C = A @ B^T (+bias/epi/Res when nsplit==1). nsplit>1: raw fp32 partials to
// Cf + sp*splitStride (reduced later in ln_k / add2 kernel).
// 128x128 tile, 4 waves, BK=32, double-buffered LDS (64 KB), 1 barrier/kstep.
__global__ __launch_bounds__(256) void mgemm_k(
    const ushort_t* __restrict__ Ah, const ushort_t* __restrict__ Al,
    const ushort_t* __restrict__ Bh, const ushort_t* __restrict__ Bl,
    const float* __restrict__ bias, const float* __restrict__ Res,
    float* __restrict__ Cf, ushort_t* __restrict__ Chh, ushort_t* __restrict__ Cll,
    int M, int N, int K, int epi, int Mslice, int Nt, int nsplit,
    int kstepsPer, long long splitStride)
{
  __shared__ __align__(16) ushort_t smem[2][4][128 * 32];
  int lin = blockIdx.x;
  int xcd = lin & 7;
  int q = lin >> 3;
  int ml = q % Mslice;
  int q2 = q / Mslice;
  int nt = q2 % Nt;
  int sp = q2 / Nt;
  int mt = xcd * Mslice + ml;
  if (mt * 128 >= M) return;
  int m0 = mt * 128, n0 = nt * 128;
  int kbase = sp * kstepsPer;
  int tid = threadIdx.x;
  int lane = tid & 63, wv = tid >> 6;
  int wm = (wv >> 1) * 64, wn = (wv & 1) * 64;
  int fr = lane & 15, fq = lane >> 4;
  f32x4 acc[4][4];
  f32x4 zero = {0.f, 0.f, 0.f, 0.f};
#pragma unroll
  for (int i = 0; i < 4; ++i)
#pragma unroll
    for (int j = 0; j < 4; ++j) acc[i][j] = zero;

  auto stage = [&](int p, int ks){
    int k0 = (kbase + ks) << 5;
#pragma unroll
    for (int it = 0; it < 8; ++it) {
      int c = tid + it * 256;            // buf uniform per wave (256-aligned)
      int buf = c >> 9;
      int cc = c & 511;
      int row = cc >> 2, cb = (cc & 3) * 8;
      const ushort_t* gsrc;
      long long grow;
      if (buf < 2) { int ar = m0 + row; if (ar >= M) ar = M - 1; grow = ar;
                     gsrc = buf ? Al : Ah; }
      else         { int br = n0 + row; if (br >= N) br = N - 1; grow = br;
                     gsrc = (buf == 2) ? Bh : Bl; }
      __builtin_amdgcn_global_load_lds((GU32*)(gsrc + grow * K + k0 + cb),
                                       (LU32*)(&smem[p][buf][0] + cc * 8), 16, 0, 0);
    }
  };

  int p = 0;
  stage(0, 0);
  for (int ks = 0; ks < kstepsPer; ++ks) {
    __syncthreads();                       // buf p ready; prev reads done
    if (ks + 1 < kstepsPer) stage(p ^ 1, ks + 1);  // prefetch during compute
    bf16x8 ah[4], al[4], bh8[4], bl8[4];
#pragma unroll
    for (int i = 0; i < 4; ++i) {
      ah[i]  = *(const bf16x8*)(&smem[p][0][0] + (wm + i * 16 + fr) * 32 + fq * 8);
      al[i]  = *(const bf16x8*)(&smem[p][1][0] + (wm + i * 16 + fr) * 32 + fq * 8);
      bh8[i] = *(const bf16x8*)(&smem[p][2][0] + (wn + i * 16 + fr) * 32 + fq * 8);
      bl8[i] = *(const bf16x8*)(&smem[p][3][0] + (wn + i * 16 + fr) * 32 + fq * 8);
    }
#pragma unroll
    for (int i = 0; i < 4; ++i)
#pragma unroll
      for (int j = 0; j < 4; ++j) {
        acc[i][j] = __builtin_amdgcn_mfma_f32_16x16x32_bf16(ah[i], bh8[j], acc[i][j], 0, 0, 0);
        acc[i][j] = __builtin_amdgcn_mfma_f32_16x16x32_bf16(ah[i], bl8[j], acc[i][j], 0, 0, 0);
        acc[i][j] = __builtin_amdgcn_mfma_f32_16x16x32_bf16(al[i], bh8[j], acc[i][j], 0, 0, 0);
      }
    p ^= 1;
  }

  if (nsplit > 1) {
    float* Cs = Cf + (long long)sp * splitStride;
#pragma unroll
    for (int i = 0; i < 4; ++i)
#pragma unroll
      for (int j = 0; j < 4; ++j) {
        int col = n0 + wn + j * 16 + fr;
        if (col >= N) continue;
#pragma unroll
        for (int r = 0; r < 4; ++r) {
          int row = m0 + wm + i * 16 + fq * 4 + r;
          if (row >= M) continue;
          Cs[(long long)row * N + col] = acc[i][j][r];
        }
      }
    return;
  }
#pragma unroll
  for (int i = 0; i < 4; ++i) {
#pragma unroll
    for (int j = 0; j < 4; ++j) {
      int col = n0 + wn + j * 16 + fr;
      if (col >= N) continue;
#pragma unroll
      for (int r = 0; r < 4; ++r) {
        int row = m0 + wm + i * 16 + fq * 4 + r;
        if (row >= M) continue;
        float v = acc[i][j][r];
        if (bias) v += bias[col];
        if (epi == 1) v = fmaxf(v, 0.f);
        else if (epi == 2) v = 0.5f * v * (1.f + erff(v * 0.70710678f));
        long long idx = (long long)row * N + col;
        if (Res) v += Res[idx];
        if (Cf) Cf[idx] = v;
        if (Chh) {
          unsigned short h = f2bf(v);
          Chh[idx] = h;
          Cll[idx] = f2bf(v - bf2f(h));
        }
      }
    }
  }
}

// PRED = s0 + s1 + bias[col]
__global__ void add_bias2_k(const float* __restrict__ s0, const float* __restrict__ s1,
                            const float* __restrict__ bias, float* __restrict__ o,
                            int total, int N){
  int idx = blockIdx.x * 256 + threadIdx.x;
  if (idx >= total) return;
  o[idx] = s0[idx] + s1[idx] + bias[idx % N];
}

// ------------------------- attention kernels -------------------------------
#define BND_ROWS 64
#define BND_STAGE 73
__global__ __launch_bounds__(256) void attn_band(
    const float* __restrict__ QKV,
    ushort_t* __restrict__ oh, ushort_t* __restrict__ ol, int S, int nrb)
{
  __shared__ float Kl[BND_STAGE][68];
  __shared__ float Vl[BND_STAGE][68];
  __shared__ float Ql[BND_ROWS][68];
  __shared__ float sc[BND_ROWS][12];
  int bh = blockIdx.x / nrb, rblk = blockIdx.x % nrb;
  int b = bh / 6, h = bh % 6;
  int r0 = 1 + rblk * BND_ROWS;
  int nrows = S - r0; if (nrows > BND_ROWS) nrows = BND_ROWS;
  int lo0 = r0 - 5; if (lo0 < 0) lo0 = 0;
  int hi0 = r0 + nrows - 1 + 4; if (hi0 > S - 1) hi0 = S - 1;
  int cnt = hi0 - lo0 + 1;
  int t = threadIdx.x;
  const float* base = QKV + ((long long)(b * S + lo0)) * 1536 + h * 64;
  for (int idx = t; idx < cnt * 64; idx += 256) {
    int row = idx >> 6, d = idx & 63;
    Kl[row][d] = base[(long long)row * 1536 + 512 + d];
    Vl[row][d] = base[(long long)row * 1536 + 1024 + d];
  }
  const float* qbase = QKV + ((long long)(b * S + r0)) * 1536 + h * 64;
  for (int idx = t; idx < nrows * 64; idx += 256) {
    int row = idx >> 6, d = idx & 63;
    Ql[row][d] = qbase[(long long)row * 1536 + d];
  }
  __syncthreads();
  for (int p = t; p < nrows * 10; p += 256) {
    int ri = p / 10, jo = p - ri * 10;
    int r = r0 + ri;
    int lo = r - 5; if (lo < 0) lo = 0;
    int hi = r + 4; if (hi > S - 1) hi = S - 1;
    int j = lo + jo;
    float s;
    if (j > hi) s = -FLT_MAX;
    else {
      int jl = j - lo0;
      float a = 0.f;
      const float4* qv = (const float4*)&Ql[ri][0];
      const float4* kv = (const float4*)&Kl[jl][0];
#pragma unroll
      for (int c = 0; c < 16; ++c) {
        float4 x = qv[c], y = kv[c];
        a += x.x * y.x + x.y * y.y + x.z * y.z + x.w * y.w;
      }
      s = a * 0.125f;
    }
    sc[ri][jo] = s;
  }
  __syncthreads();
  if (t < nrows) {
    float mx = -FLT_MAX;
#pragma unroll
    for (int jo = 0; jo < 10; ++jo) mx = fmaxf(mx, sc[t][jo]);
    float pv[10]; float sum = 0.f;
#pragma unroll
    for (int jo = 0; jo < 10; ++jo) {
      float s = sc[t][jo];
      float e = (s == -FLT_MAX) ? 0.f : expf(s - mx);
      pv[jo] = e; sum += e;
    }
    float inv = 1.f / sum;
#pragma unroll
    for (int jo = 0; jo < 10; ++jo) sc[t][jo] = pv[jo] * inv;
  }
  __syncthreads();
  for (int idx = t; idx < nrows * 64; idx += 256) {
    int ri = idx >> 6, d = idx & 63;
    int r = r0 + ri;
    int lo = r - 5; if (lo < 0) lo = 0;
    int jbase = lo - lo0;
    float a = 0.f;
#pragma unroll
    for (int jo = 0; jo < 10; ++jo) {
      int jl = jbase + jo; if (jl >= cnt) jl = cnt - 1;
      a += sc[ri][jo] * Vl[jl][d];
    }
    long long o = ((long long)(b * S + r)) * 512 + h * 64 + d;
    unsigned short hh = f2bf(a);
    oh[o] = hh; ol[o] = f2bf(a - bf2f(hh));
  }
}

__global__ __launch_bounds__(256) void attn_full(
    const float* __restrict__ QKV,
    ushort_t* __restrict__ oh, ushort_t* __restrict__ ol, int S)
{
  __shared__ float sm_m[4], sm_l[4], sm_acc[4][64];
  int idx = blockIdx.x;
  int b, h, i;
  if (idx < B_ * H_) { b = idx >> 3; h = idx & 7; i = 0; }
  else { int r = idx - B_ * H_; h = 6 + r / (S - 1); i = 1 + r % (S - 1); b = 0; }
  int t = threadIdx.x, lane = t & 63, w = t >> 6;
  const float* Qr = QKV + ((long long)(b * S + i)) * 1536 + h * 64;
  const float* Kb = QKV + ((long long)(b * S)) * 1536 + 512 + h * 64;
  const float* Vb = QKV + ((long long)(b * S)) * 1536 + 1024 + h * 64;
  float q = Qr[lane];
  float m = -FLT_MAX, l = 0.f, acc = 0.f;
  for (int j0 = w * 4; j0 < S; j0 += 16) {
    float s[4];
#pragma unroll
    for (int c = 0; c < 4; ++c) {
      int j = j0 + c;
      float kv = (j < S) ? Kb[(long long)j * 1536 + lane] : 0.f;
      float r = waveReduceSum(q * kv);
      s[c] = r * 0.125f;
    }
#pragma unroll
    for (int c = 0; c < 4; ++c) {
      s[c] = __shfl(s[c], 0);
      if (j0 + c >= S) s[c] = -FLT_MAX;
    }
    float mc = fmaxf(fmaxf(s[0], s[1]), fmaxf(s[2], s[3]));
    float mn = fmaxf(m, mc);
    float scale = (m == -FLT_MAX) ? 0.f : expf(m - mn);
    float lsum = 0.f, vsum = 0.f;
#pragma unroll
    for (int c = 0; c < 4; ++c) {
      int j = j0 + c;
      if (j < S) {
        float p = expf(s[c] - mn);
        lsum += p;
        vsum += p * Vb[(long long)j * 1536 + lane];
      }
    }
    acc = acc * scale + vsum;
    l = l * scale + lsum;
    m = mn;
  }
  sm_m[w] = m;
  sm_l[w] = l;
  sm_acc[w][lane] = acc;
  __syncthreads();
  if (t < 64) {
    float M = fmaxf(fmaxf(sm_m[0], sm_m[1]), fmaxf(sm_m[2], sm_m[3]));
    float L = 0.f, A = 0.f;
#pragma unroll
    for (int w2 = 0; w2 < 4; ++w2) {
      float e = (sm_m[w2] == -FLT_MAX) ? 0.f : expf(sm_m[w2] - M);
      L += sm_l[w2] * e;
      A += sm_acc[w2][t] * e;
    }
    float ctx = A / L;
    long long o = ((long long)(b * S + i)) * 512 + h * 64 + t;
    unsigned short hh = f2bf(ctx);
    oh[o] = hh; ol[o] = f2bf(ctx - bf2f(hh));
  }
}

__global__ __launch_bounds__(256) void attn_unif(
    const float* __restrict__ QKV,
    ushort_t* __restrict__ oh, ushort_t* __restrict__ ol, int S)
{
  __shared__ float part[4][64];
  __shared__ float vm[64];
  int blk = blockIdx.x;
  int b = 1 + (blk >> 1), h = 6 + (blk & 1);
  int t = threadIdx.x, lane = t & 63, w = t >> 6;
  const float* Vb = QKV + ((long long)(b * S)) * 1536 + 1024 + h * 64;
  float s = 0.f;
  for (int j = w; j < S; j += 4) s += Vb[(long long)j * 1536 + lane];
  part[w][lane] = s;
  __syncthreads();
  if (t < 64) vm[t] = (part[0][t] + part[1][t] + part[2][t] + part[3][t]) * (1.f / S);
  __syncthreads();
  float m = vm[lane];
  unsigned short hh = f2bf(m);
  unsigned short hl = f2bf(m - bf2f(hh));
  for (int i = 1 + w; i < S; i += 4) {
    long long o = ((long long)(b * S + i)) * 512 + h * 64 + lane;
    oh[o] = hh; ol[o] = hl;
  }
}

// ------------------------- conversion kernels ------------------------------
__global__ void conv_hl(const float* __restrict__ x, ushort_t* __restrict__ h,
                        ushort_t* __restrict__ l, long long n){
  long long i = (long long)blockIdx.x * 256 + threadIdx.x;
  if (i >= n) return;
  float v = x[i];
  unsigned short hh = f2bf(v);
  h[i] = hh;
  l[i] = f2bf(v - bf2f(hh));
}

__global__ void conv_qkv(const float* __restrict__ Wq, const float* __restrict__ Wk,
                         const float* __restrict__ Wv,
                         ushort_t* __restrict__ h, ushort_t* __restrict__ l){
  int idx = blockIdx.x * 256 + threadIdx.x;
  if (idx >= L_ * 1536 * 512) return;
  int li = idx / (1536 * 512);
  int r = (idx / 512) % 1536;
  int c = idx & 511;
  const float* W = (r < 512) ? Wq : (r < 1024) ? Wk : Wv;
  int rr = r & 511;
  float v = W[(long long)li * 262144 + rr * 512 + c];
  unsigned short hh = f2bf(v);
  h[idx] = hh;
  l[idx] = f2bf(v - bf2f(hh));
}

__global__ void pack_bqkv(const float* __restrict__ bq, const float* __restrict__ bk,
                          const float* __restrict__ bv, float* __restrict__ o){
  int idx = blockIdx.x * 256 + threadIdx.x;
  if (idx >= L_ * 1536) return;
  int l = idx / 1536, r = idx % 1536;
  o[idx] = (r < 512) ? bq[l * 512 + r] : (r < 1024) ? bk[l * 512 + r - 512]
                                                    : bv[l * 512 + r - 1024];
}

__global__ void build_tcfw_hl(const float* __restrict__ w,
                              ushort_t* __restrict__ h, ushort_t* __restrict__ l){
  int idx = blockIdx.x * 256 + threadIdx.x;
  if (idx >= 512 * 320) return;
  int r = idx / 320, c = idx - r * 320;
  float v = (c < 300) ? w[r * 300 + c] : 0.f;
  unsigned short hh = f2bf(v);
  h[idx] = hh;
  l[idx] = f2bf(v - bf2f(hh));
}

// ------------------------- small kernels -----------------------------------
__global__ void build_wcat(const float* __restrict__ cw1, const float* __restrict__ cw2,
                           const float* __restrict__ cw3, float* __restrict__ w){
  int idx = blockIdx.x * 256 + threadIdx.x;
  if (idx >= 600 * 1024) return;
  int o = idx >> 10, c = idx & 1023;
  float v;
  if      (o < 100) v = cw1[o * 1024 + c];
  else if (o < 200) v = cw2[(o - 100) * 2048 + c];
  else if (o < 300) v = cw2[(o - 200) * 2048 + 1024 + c];
  else if (o < 400) v = cw3[(o - 300) * 3072 + c];
  else if (o < 500) v = cw3[(o - 400) * 3072 + 1024 + c];
  else              v = cw3[(o - 500) * 3072 + 2048 + c];
  w[idx] = v;
}

__global__ void build_wcat_hl(const float* __restrict__ cw1, const float* __restrict__ cw2,
                              const float* __restrict__ cw3,
                              ushort_t* __restrict__ wh, ushort_t* __restrict__ wl){
  int idx = blockIdx.x * 256 + threadIdx.x;
  if (idx >= 640 * 1024) return;
  int o = idx >> 10, c = idx & 1023;
  float v = 0.f;
  if      (o < 100) v = cw1[o * 1024 + c];
  else if (o < 200) v = cw2[(o - 100) * 2048 + c];
  else if (o < 300) v = cw2[(o - 200) * 2048 + 1024 + c];
  else if (o < 400) v = cw3[(o - 300) * 3072 + c];
  else if (o < 500) v = cw3[(o - 400) * 3072 + 1024 + c];
  else if (o < 600) v = cw3[(o - 500) * 3072 + 2048 + c];
  unsigned short h = f2bf(v);
  wh[idx] = h;
  wl[idx] = f2bf(v - bf2f(h));
}

__global__ void feats_k(const float* __restrict__ proj, const int* __restrict__ src,
                        const float* __restrict__ cb1, const float* __restrict__ cb2,
                        const float* __restrict__ cb3, float* __restrict__ feats, int ld){
  __shared__ int ids[TOK_];
  int n = blockIdx.x;
  int t = threadIdx.x;
  if (t < TOK_) ids[t] = src[n * TOK_ + t];
  __syncthreads();
  if (t >= 300) return;
  float bia, m = -FLT_MAX;
  if (t < 100) {
    bia = cb1[t];
    for (int k = 0; k < 50; ++k)
      m = fmaxf(m, proj[(long long)ids[k] * ld + t]);
  } else if (t < 200) {
    int o = t - 100; bia = cb2[o];
    for (int k = 0; k < 49; ++k)
      m = fmaxf(m, proj[(long long)ids[k] * ld + 100 + o] +
                   proj[(long long)ids[k + 1] * ld + 200 + o]);
  } else {
    int o = t - 200; bia = cb3[o];
    for (int k = 0; k < 48; ++k)
      m = fmaxf(m, proj[(long long)ids[k] * ld + 300 + o] +
                   proj[(long long)ids[k + 1] * ld + 400 + o] +
                   proj[(long long)ids[k + 2] * ld + 500 + o]);
  }
  feats[(long long)n * 300 + t] = fmaxf(m + bia, 0.f);
}

__global__ void feats_hl_k(const float* __restrict__ proj, const int* __restrict__ src,
                           const float* __restrict__ cb1, const float* __restrict__ cb2,
                           const float* __restrict__ cb3,
                           ushort_t* __restrict__ fh, ushort_t* __restrict__ fl, int ld){
  __shared__ int ids[TOK_];
  int n = blockIdx.x;
  int t = threadIdx.x;               // 320 threads
  if (t < TOK_) ids[t] = src[n * TOK_ + t];
  __syncthreads();
  float a = 0.f;
  if (t < 300) {
    float bia, m = -FLT_MAX;
    if (t < 100) {
      bia = cb1[t];
      for (int k = 0; k < 50; ++k)
        m = fmaxf(m, proj[(long long)ids[k] * ld + t]);
    } else if (t < 200) {
      int o = t - 100; bia = cb2[o];
      for (int k = 0; k < 49; ++k)
        m = fmaxf(m, proj[(long long)ids[k] * ld + 100 + o] +
                     proj[(long long)ids[k + 1] * ld + 200 + o]);
    } else {
      int o = t - 200; bia = cb3[o];
      for (int k = 0; k < 48; ++k)
        m = fmaxf(m, proj[(long long)ids[k] * ld + 300 + o] +
                     proj[(long long)ids[k + 1] * ld + 400 + o] +
                     proj[(long long)ids[k + 2] * ld + 500 + o]);
    }
    a = fmaxf(m + bia, 0.f);
  }
  long long o = (long long)n * 320 + t;
  unsigned short hh = f2bf(a);
  fh[o] = hh;
  fl[o] = f2bf(a - bf2f(hh));
}

// LayerNorm. Input = sum of nsplit slices (stride sstr) + bias2, then epi2
// (0 none / 1 relu / 2 gelu), then +res2, then LN (+affine/post), fp32 out,
// optional bf16 hi/lo pair out.
__global__ __launch_bounds__(256) void ln_k(
    const float* __restrict__ in, long long sstr, int nsplit,
    const float* __restrict__ bias2, const float* __restrict__ res2, int epi2,
    float* __restrict__ out, const float* __restrict__ g, const float* __restrict__ bta,
    ushort_t* __restrict__ oh, ushort_t* __restrict__ ol,
    const float* __restrict__ pscale, const float* __restrict__ pbias, int S)
{
  __shared__ float sm[4];
  long long row = blockIdx.x;
  int t = threadIdx.x;
  const float* x = in + row * E_;
  float v0 = x[t], v1 = x[t + 256];
  for (int s = 1; s < nsplit; ++s) {
    v0 += x[(long long)s * sstr + t];
    v1 += x[(long long)s * sstr + t + 256];
  }
  if (bias2) { v0 += bias2[t]; v1 += bias2[t + 256]; }
  if (epi2 == 1) { v0 = fmaxf(v0, 0.f); v1 = fmaxf(v1, 0.f); }
  else if (epi2 == 2) {
    v0 = 0.5f * v0 * (1.f + erff(v0 * 0.70710678f));
    v1 = 0.5f * v1 * (1.f + erff(v1 * 0.70710678f));
  }
  if (res2) { v0 += res2[row * E_ + t]; v1 += res2[row * E_ + t + 256]; }
  float* y = out + row * E_;
  float mu = blockReduceSum256(v0 + v1, sm) * (1.f / E_);
  float d0 = v0 - mu, d1 = v1 - mu;
  float var = blockReduceSum256(d0 * d0 + d1 * d1, sm) * (1.f / E_);
  float r = rsqrtf(var + 1e-12f);
  float o0 = d0 * r, o1 = d1 * r;
  if (g) { o0 = o0 * g[t] + bta[t]; o1 = o1 * g[t + 256] + bta[t + 256]; }
  if (pscale) {
    long long b = row / S, s = row % S;
    long long off = (b * 300 + s) * E_;
    o0 = o0 * pscale[off + t] + pbias[off + t];
    o1 = o1 * pscale[off + t + 256] + pbias[off + t + 256];
  }
  y[t] = o0; y[t + 256] = o1;
  if (oh) {
    unsigned short h0 = f2bf(o0), h1 = f2bf(o1);
    oh[row * E_ + t] = h0;       oh[row * E_ + t + 256] = h1;
    ol[row * E_ + t] = f2bf(o0 - bf2f(h0));
    ol[row * E_ + t + 256] = f2bf(o1 - bf2f(h1));
  }
}

__global__ void build_x1(const float* __restrict__ xln, float* __restrict__ x1){
  long long idx = (long long)blockIdx.x * 256 + threadIdx.x;
  if (idx >= 3232LL * 512) return;
  long long row = idx >> 9; int c = (int)(idx & 511);
  long long b = row / 101, s = row % 101;
  x1[idx] = (s == 0) ? 0.f : xln[((b * 200) + (s - 1)) * 512 + c];
}

__global__ __launch_bounds__(256) void attn_softmax(float* __restrict__ sc, int S){
  __shared__ float sm[4];
  long long row = blockIdx.x;
  int i = (int)(row % S); long long bh = row / S;
  int h = (int)(bh & 7); int b = (int)(bh >> 3);
  float* p = sc + row * S;
  int t = threadIdx.x;
  bool inr = t < S;
  bool allow;
  if (i == 0) allow = true;
  else if (h < 6) allow = (t >= i - 5) && (t <= i + 4);
  else allow = (b == 0);
  float v = inr ? (allow ? p[t] : -1e9f) : -FLT_MAX;
  float mx = blockReduceMax256(v, sm);
  float e = inr ? expf(v - mx) : 0.f;
  float s = blockReduceSum256(e, sm);
  if (inr) p[t] = e / s;
}

__global__ __launch_bounds__(256) void softmax_rows(const float* __restrict__ in,
                                                    float* __restrict__ out, int n){
  __shared__ float sm[4];
  long long row = blockIdx.x;
  const float* x = in + row * n;
  float* y = out + row * n;
  int t = threadIdx.x;
  float v0 = (t < n) ? x[t] : -FLT_MAX;
  float v1 = (t + 256 < n) ? x[t + 256] : -FLT_MAX;
  float mx = blockReduceMax256(fmaxf(v0, v1), sm);
  float e0 = (t < n) ? expf(v0 - mx) : 0.f;
  float e1 = (t + 256 < n) ? expf(v1 - mx) : 0.f;
  float s = blockReduceSum256(e0 + e1, sm);
  if (t < n) y[t] = e0 / s;
  if (t + 256 < n) y[t + 256] = e1 / s;
}

__global__ void copy_cls(const float* __restrict__ pred, float* __restrict__ cls){
  int idx = blockIdx.x * 256 + threadIdx.x;
  if (idx >= B_ * 200) return;
  int b = idx / 200, m = idx % 200;
  cls[idx] = pred[(long long)b * 101 * 200 + m];
}

__global__ __launch_bounds__(256) void tokvec_k(const float* __restrict__ lsoft,
                         const float* __restrict__ tokmat,
                         const float* __restrict__ cls, float* __restrict__ tv){
  __shared__ float sm[4];
  int bn = blockIdx.x; int b = bn / 200, n = bn % 200;
  int t = threadIdx.x;
  float s = 0.f;
  if (t < 200)
    s = (lsoft[n * 200 + t] + 0.4f * tokmat[((long long)b * 200 + n) * 200 + t]) * cls[b * 200 + t];
  float tot = blockReduceSum256(s, sm);
  if (t == 0) tv[bn] = tot;
}

__global__ __launch_bounds__(256) void seg_soft_k(const float* __restrict__ pred,
                         const float* __restrict__ allp,
                         float* __restrict__ c0, float* __restrict__ c1,
                         float* __restrict__ a0, float* __restrict__ a1){
  __shared__ float sm[4];
  int b = blockIdx.x, which = blockIdx.y;
  const float* srcp; int C;
  if (which < 2) { srcp = pred; C = 200; } else { srcp = allp; C = 512; }
  int i = which & 1;
  int start = i, cnt = i ? 199 : 100;
  float* dst = (which == 0) ? c0 : (which == 1) ? c1 : (which == 2) ? a0 : a1;
  const float* base = srcp + ((long long)b * 200 + start) * C;
  int t = threadIdx.x;
  float m0 = 0.f, m1 = 0.f;
  for (int r = 0; r < cnt; ++r) {
    if (t < C)       m0 += base[(long long)r * C + t];
    if (t + 256 < C) m1 += base[(long long)r * C + t + 256];
  }
  float inv = 1.f / cnt;
  m0 *= inv; m1 *= inv;
  float v0 = (t < C) ? m0 : -FLT_MAX;
  float v1 = (t + 256 < C) ? m1 : -FLT_MAX;
  float mx = blockReduceMax256(fmaxf(v0, v1), sm);
  float e0 = (t < C) ? expf(v0 - mx) : 0.f;
  float e1 = (t + 256 < C) ? expf(v1 - mx) : 0.f;
  float s = blockReduceSum256(e0 + e1, sm);
  if (t < C)       dst[(long long)b * C + t] = e0 / s;
  if (t + 256 < C) dst[(long long)b * C + t + 256] = e1 / s;
}

__global__ __launch_bounds__(256) void loss_partial_k(const float* __restrict__ c0,
                         const float* __restrict__ c1,
                         const float* __restrict__ a0, const float* __restrict__ a1,
                         float* __restrict__ partial){
  __shared__ float sm[4];
  int b = blockIdx.x, t = threadIdx.x;
  float k01 = 0.f, k10 = 0.f;
  if (t < 200) {
    float x = c0[b * 200 + t] + 1e-6f, y = c1[b * 200 + t] + 1e-6f;
    k01 = x * logf(x / y);
    k10 = y * logf(y / x);
  }
  float K01 = blockReduceSum256(k01, sm);
  float K10 = blockReduceSum256(k10, sm);
  float d0 = a0[b * 512 + t] - a1[b * 512 + t];
  float d1 = a0[b * 512 + t + 256] - a1[b * 512 + t + 256];
  float E2 = blockReduceSum256(d0 * d0 + d1 * d1, sm);
  if (t == 0) {
    float euc = sqrtf(fmaxf(E2, 1e-12f));
    float kv[4] = {0.f, K01 * 10.f, K10 * 10.f, 0.f};
    float ev[4] = {1e-6f, euc, euc, 1e-6f};
    float mk = fmaxf(fmaxf(kv[0], kv[1]), fmaxf(kv[2], kv[3]));
    float me = fmaxf(fmaxf(ev[0], ev[1]), fmaxf(ev[2], ev[3]));
    float sk = 0.f, se = 0.f;
    for (int q = 0; q < 4; ++q) { kv[q] = expf(kv[q] - mk); sk += kv[q];
                                  ev[q] = expf(ev[q] - me); se += ev[q]; }
    float p = 0.f;
    for (int q = 0; q < 4; ++q) {
      float aa = kv[q] / sk + 1e-6f, bb = ev[q] / se + 1e-6f;
      p += aa * logf(aa / bb);
    }
    partial[b] = p;
  }
}

__global__ void loss_final_k(const float* __restrict__ partial, float* __restrict__ out){
  if (threadIdx.x == 0) {
    float s = 0.f;
    for (int b = 0; b < B_; ++b) s += partial[b];
    out[0] = s * (100000.f * 0.2f / B_);
  }
}

// ---------------------------------------------------------------------------
extern "C" void kernel_launch(void* const* d_in, const int* in_sizes, int n_in,
                              void* d_out, int out_size, void* d_ws, size_t ws_size,
                              hipStream_t stream) {
  const int*   src   = (const int*)  d_in[0];
  const float* lab   = (const float*)d_in[1];
  const float* emb   = (const float*)d_in[2];
  const float* cw1   = (const float*)d_in[3];
  const float* cb1   = (const float*)d_in[4];
  const float* cw2   = (const float*)d_in[5];
  const float* cb2   = (const float*)d_in[6];
  const float* cw3   = (const float*)d_in[7];
  const float* cb3   = (const float*)d_in[8];
  const float* tcfw  = (const float*)d_in[9];
  const float* tcfb  = (const float*)d_in[10];
  const float* Wq    = (const float*)d_in[11];
  const float* bq    = (const float*)d_in[12];
  const float* Wk    = (const float*)d_in[13];
  const float* bk    = (const float*)d_in[14];
  const float* Wv    = (const float*)d_in[15];
  const float* bv    = (const float*)d_in[16];
  const float* Wo    = (const float*)d_in[17];
  const float* bo    = (const float*)d_in[18];
  const float* W1    = (const float*)d_in[19];
  const float* b1v   = (const float*)d_in[20];
  const float* W2    = (const float*)d_in[21];
  const float* b2v   = (const float*)d_in[22];
  const float* g1    = (const float*)d_in[23];
  const float* be1   = (const float*)d_in[24];
  const float* g2    = (const float*)d_in[25];
  const float* be2   = (const float*)d_in[26];
  const float* fc1w  = (const float*)d_in[27];
  const float* fc1b  = (const float*)d_in[28];
  const float* fc2w  = (const float*)d_in[29];
  const float* fc2b  = (const float*)d_in[30];
  const float* fc3w  = (const float*)d_in[31];
  const float* fc3b  = (const float*)d_in[32];
  const float* pscale= (const float*)d_in[33];
  const float* pbias = (const float*)d_in[34];
  float* out = (float*)d_out;
  float* ws  = (float*)d_ws;
  ushort_t* wsu = (ushort_t*)d_ws;

  const size_t NEED_MFMA = 215200000ULL;

  if (ws_size >= NEED_MFMA) {
    // =================== MFMA path ===================
    const long long P_EMBH  = 0;
    const long long P_EMBL  = 6412800;
    const long long P_WCATH = 12825600;
    const long long P_WCATL = 13153280;
    const long long P_PROJ  = 13480960;     // 12525*640
    const long long P_FEATS = 21496960;     // FH/FL (ushort) region
    const long long SZW4 = 6LL * 512 * 512;        // 1,572,864
    const long long SZW1 = 6LL * 2048 * 512;       // 6,291,456
    const long long UQKVH = 0;                     // 3*SZW4 (L,1536,512)
    const long long UQKVL = 3 * SZW4;
    const long long UOH = 6 * SZW4, UOL = 7 * SZW4;
    const long long U1H = 8 * SZW4,            U1L = 8 * SZW4 + SZW1;
    const long long U2H = 8 * SZW4 + 2 * SZW1, U2L = 8 * SZW4 + 3 * SZW1;
    const long long UF1H = 8 * SZW4 + 4 * SZW1, UF1L = UF1H + 262144;
    const long long O_BIG  = 19136512;      // 13,107,200 fl (FFN bf16 pair)
    const long long O_XLN  = 32243712;      // 3,276,800
    const long long O_X1   = 35520512;      // 1,654,784
    const long long O_QKV  = 37175296;      // 9,830,400 (QKV fp32 / split slices)
    const long long O_TMP  = 47005696;      // 3,276,800 (slice-3 overflow / ALLP)
    const long long O_XH   = 50282496;      // ushort pair
    const long long O_XL   = 51920896;
    const long long O_SM   = 53559296;
    const long long O_LSOFT= O_SM;
    const long long O_CLS  = O_LSOFT + 40000;
    const long long O_TV   = O_CLS + 6400;
    const long long O_C0   = O_TV + 6400;
    const long long O_C1   = O_C0 + 6400;
    const long long O_A0   = O_C1 + 6400;
    const long long O_A1   = O_A0 + 16384;
    const long long O_PART = O_A1 + 16384;  // 64
    const long long O_BQKV = O_PART + 64;   // 9216
    const long long O_FC2W = O_BQKV + 9216; // 102,400 fl (hi+lo ushort)

    ushort_t* EMBH = (ushort_t*)(ws + P_EMBH);
    ushort_t* EMBL = (ushort_t*)(ws + P_EMBL);
    ushort_t* WCATH= (ushort_t*)(ws + P_WCATH);
    ushort_t* WCATL= (ushort_t*)(ws + P_WCATL);
    float* PROJ = ws + P_PROJ;
    ushort_t* FH = (ushort_t*)(ws + P_FEATS);           // 6400x320
    ushort_t* FL = FH + 6400LL * 320;
    float* BIG  = ws + O_BIG;
    float* XLN  = ws + O_XLN;
    float* X1   = ws + O_X1;
    float* QKV  = ws + O_QKV;      // also SPLIT base (spans into TMP for 4-way)
    float* TMP  = ws + O_TMP;      // also ALLP in post
    ushort_t* TCFWH = (ushort_t*)(ws + O_TMP);          // pre-encoder only
    ushort_t* TCFWL = TCFWH + 512 * 320;
    ushort_t* XH = (ushort_t*)(ws + O_XH);
    ushort_t* XL = (ushort_t*)(ws + O_XL);
    float* LSOFT= ws + O_LSOFT;
    float* CLS  = ws + O_CLS;
    float* TV   = ws + O_TV;
    float* C0p  = ws + O_C0;
    float* C1p  = ws + O_C1;
    float* A0p  = ws + O_A0;
    float* A1p  = ws + O_A1;
    float* PART = ws + O_PART;
    float* BQKV = ws + O_BQKV;
    ushort_t* FC2WH = (ushort_t*)(ws + O_FC2W);
    ushort_t* FC2WL = FC2WH + 200 * 512;
    float* SPLIT = QKV;
    float* ALLP  = TMP;
    float* PRED  = QKV;                        // R x 200 (after slices dead)
    float* FC2S  = QKV + 6553600;              // fc2 split slices (2 x R*200)
    float* TOKMAT= QKV + 3276800;              // B x 200 x 200

    auto mgemm = [&](const ushort_t* Ah, const ushort_t* Al,
                     const ushort_t* Bh, const ushort_t* Bl,
                     const float* bias, const float* Res, float* Cf,
                     ushort_t* Ch, ushort_t* Cl, int M, int N, int K, int epi,
                     int nsplit, long long splitStride){
      int Mt = (M + 127) / 128;
      int Nt = (N + 127) / 128;
      int Mslice = (Mt + 7) / 8;
      int kst = (K / nsplit) >> 5;
      dim3 g(8 * Mslice * Nt * nsplit);
      mgemm_k<<<g, 256, 0, stream>>>(Ah, Al, Bh, Bl, bias, Res, Cf, Ch, Cl,
                                     M, N, K, epi, Mslice, Nt, nsplit, kst, splitStride);
    };

    // ---------------- TextCNN ----------------
    conv_hl<<<(VOC_ * TCE_ + 255) / 256, 256, 0, stream>>>(emb, EMBH, EMBL, (long long)VOC_ * TCE_);
    build_wcat_hl<<<(640 * 1024 + 255) / 256, 256, 0, stream>>>(cw1, cw2, cw3, WCATH, WCATL);
    mgemm(EMBH, EMBL, WCATH, WCATL, nullptr, nullptr, PROJ, nullptr, nullptr,
          VOC_, 640, TCE_, 0, 1, 0);
    feats_hl_k<<<B_ * SEQ_, 320, 0, stream>>>(PROJ, src, cb1, cb2, cb3, FH, FL, 640);
    build_tcfw_hl<<<(512 * 320 + 255) / 256, 256, 0, stream>>>(tcfw, TCFWH, TCFWL);
    // x_all: split-2 raw -> SPLIT (QKV region only), reduce+bias+LN in ln_k
    mgemm(FH, FL, TCFWH, TCFWL, nullptr, nullptr, SPLIT, nullptr, nullptr,
          B_ * SEQ_, E_, 320, 0, 2, 6400LL * 512);
    ln_k<<<B_ * SEQ_, 256, 0, stream>>>(SPLIT, 6400LL * 512, 2, tcfb, nullptr, 0,
                                        XLN, nullptr, nullptr, nullptr, nullptr,
                                        nullptr, nullptr, SEQ_);
    build_x1<<<(3232 * 512 + 255) / 256, 256, 0, stream>>>(XLN, X1);

    // ---------------- weight conversion ----------------
    conv_qkv<<<(L_ * 1536 * 512 + 255) / 256, 256, 0, stream>>>(Wq, Wk, Wv,
                                                                wsu + UQKVH, wsu + UQKVL);
    pack_bqkv<<<(L_ * 1536 + 255) / 256, 256, 0, stream>>>(bq, bk, bv, BQKV);
    conv_hl<<<(int)((SZW4 + 255) / 256), 256, 0, stream>>>(Wo, wsu + UOH, wsu + UOL, SZW4);
    conv_hl<<<(int)((SZW1 + 255) / 256), 256, 0, stream>>>(W1, wsu + U1H, wsu + U1L, SZW1);
    conv_hl<<<(int)((SZW1 + 255) / 256), 256, 0, stream>>>(W2, wsu + U2H, wsu + U2L, SZW1);
    conv_hl<<<(262144 + 255) / 256, 256, 0, stream>>>(fc1w, wsu + UF1H, wsu + UF1L, 262144);
    conv_hl<<<(200 * 512 + 255) / 256, 256, 0, stream>>>(fc2w, FC2WH, FC2WL, 200 * 512);

    // ---------------- encoder ----------------
    auto encoder = [&](float* X, int S, int R){
      ushort_t* BIGH = (ushort_t*)BIG;
      ushort_t* BIGL = BIGH + (long long)R * NHID_;
      int nrb = (S - 1 + BND_ROWS - 1) / BND_ROWS;
      int nfull = B_ * H_ + 2 * (S - 1);
      long long sstr = (long long)R * E_;
      for (int l = 0; l < L_; ++l) {
        long long oq = (long long)l * 1536 * 512;
        long long o4 = (long long)l * E_ * E_;
        long long o1 = (long long)l * NHID_ * E_;
        const float* bo_l = bo + l * E_;
        const float* b1_l = b1v + l * NHID_; const float* b2_l = b2v + l * E_;
        const float* g1_l = g1 + l * E_;  const float* be1_l = be1 + l * E_;
        const float* g2_l = g2 + l * E_;  const float* be2_l = be2 + l * E_;

        mgemm(XH, XL, wsu + UQKVH + oq, wsu + UQKVL + oq, BQKV + l * 1536,
              nullptr, QKV, nullptr, nullptr, R, 1536, E_, 0, 1, 0);
        attn_band<<<B_ * 6 * nrb, 256, 0, stream>>>(QKV, XH, XL, S, nrb);
        attn_full<<<nfull, 256, 0, stream>>>(QKV, XH, XL, S);
        attn_unif<<<(B_ - 1) * 2, 256, 0, stream>>>(QKV, XH, XL, S);
        // attn-out: split-2 raw -> SPLIT; ln folds +bo +X residual
        mgemm(XH, XL, wsu + UOH + o4, wsu + UOL + o4, nullptr, nullptr,
              SPLIT, nullptr, nullptr, R, E_, E_, 0, 2, sstr);
        ln_k<<<R, 256, 0, stream>>>(SPLIT, sstr, 2, bo_l, X, 0,
                                    X, g1_l, be1_l, XH, XL, nullptr, nullptr, S);
        mgemm(XH, XL, wsu + U1H + o1, wsu + U1L + o1, b1_l, nullptr, nullptr,
              BIGH, BIGL, R, NHID_, E_, 1 /*relu*/, 1, 0);
        // FFN2: split-4 raw -> SPLIT (spans QKV+TMP); ln folds +b2 +X
        mgemm(BIGH, BIGL, wsu + U2H + o1, wsu + U2L + o1, nullptr, nullptr,
              SPLIT, nullptr, nullptr, R, E_, NHID_, 0, 4, sstr);
        ln_k<<<R, 256, 0, stream>>>(SPLIT, sstr, 4, b2_l, X, 0,
                                    X, g2_l, be2_l, XH, XL, nullptr, nullptr, S);
      }
    };

    auto post = [&](int S, int R){
      long long sstr = (long long)R * E_;
      // fc1: split-2 raw; ln folds +fc1b, gelu, then LN + post scale/bias
      mgemm(XH, XL, wsu + UF1H, wsu + UF1L, nullptr, nullptr,
            SPLIT, nullptr, nullptr, R, E_, E_, 0, 2, sstr);
      ln_k<<<R, 256, 0, stream>>>(SPLIT, sstr, 2, fc1b, nullptr, 2 /*gelu*/,
                                  ALLP, nullptr, nullptr, XH, XL, pscale, pbias, S);
      // fc2: split-2 raw -> FC2S, then add + bias -> PRED
      mgemm(XH, XL, FC2WH, FC2WL, nullptr, nullptr, FC2S,
            nullptr, nullptr, R, 200, E_, 0, 2, (long long)R * 200);
      add_bias2_k<<<(R * 200 + 255) / 256, 256, 0, stream>>>(
          FC2S, FC2S + (long long)R * 200, fc2b, PRED, R * 200, 200);
    };

    // ---------------- pass 1 (S=101) -> outputs 0,1 ----------------
    conv_hl<<<((3232 * 512) + 255) / 256, 256, 0, stream>>>(X1, XH, XL, 3232LL * 512);
    encoder(X1, 101, B_ * 101);
    post(101, B_ * 101);
    copy_cls<<<(B_ * 200 + 255) / 256, 256, 0, stream>>>(PRED, CLS);
    softmax_rows<<<B_, 256, 0, stream>>>(CLS, out + 6400, 200);     // output 1
    softmax_rows<<<200, 256, 0, stream>>>(lab, LSOFT, 200);
    launch_gemm(stream, PRED + 200, fc3w, fc3b, nullptr, TOKMAT, 200, 200, 100,
                1, 200, 100, 1, 200, 0,
                B_, 1, 101LL * 200, 0, 0, 0, 200LL * 200, 0, 1.f, 0);
    tokvec_k<<<B_ * 200, 256, 0, stream>>>(LSOFT, TOKMAT, CLS, TV);
    softmax_rows<<<B_, 256, 0, stream>>>(TV, out, 200);             // output 0

    // ---------------- pass 2 (S=200) -> loss ----------------
    conv_hl<<<((6400 * 512) + 255) / 256, 256, 0, stream>>>(XLN, XH, XL, 6400LL * 512);
    encoder(XLN, SEQ_, B_ * SEQ_);
    post(SEQ_, B_ * SEQ_);
    {
      dim3 g(B_, 4);
      seg_soft_k<<<g, 256, 0, stream>>>(PRED, ALLP, C0p, C1p, A0p, A1p);
    }
    loss_partial_k<<<B_, 256, 0, stream>>>(C0p, C1p, A0p, A1p, PART);
    loss_final_k<<<1, 64, 0, stream>>>(PART, out + 12800);          // output 2
    return;
  }

  // =================== fallback: fp32 path ===================
  const long long O_WCAT = 0;
  const long long O_PROJ = 614400;
  const long long O_FEATS= 8129400;
  const long long O_BIG  = 0;
  const long long O_XLN  = 13107200;
  const long long O_X1   = 16384000;
  const long long O_XQ   = 18038784;
  const long long O_XK   = 21315584;
  const long long O_XV   = 24592384;
  const long long O_CTX  = 27869184;
  const long long O_TMP  = 31145984;
  const long long O_SM   = 34422784;
  const long long O_LSOFT= O_SM;
  const long long O_CLS  = O_LSOFT + 40000;
  const long long O_TV   = O_CLS + 6400;
  const long long O_C0   = O_TV + 6400;
  const long long O_C1   = O_C0 + 6400;
  const long long O_A0   = O_C1 + 6400;
  const long long O_A1   = O_A0 + 16384;
  const long long O_PART = O_A1 + 16384;

  float* WCAT = ws + O_WCAT;
  float* PROJ = ws + O_PROJ;
  float* FEATS= ws + O_FEATS;
  float* BIG  = ws + O_BIG;
  float* XLN  = ws + O_XLN;
  float* X1   = ws + O_X1;
  float* XQ   = ws + O_XQ;
  float* XK   = ws + O_XK;
  float* XV   = ws + O_XV;
  float* CTX  = ws + O_CTX;
  float* TMP  = ws + O_TMP;
  float* LSOFT= ws + O_LSOFT;
  float* CLS  = ws + O_CLS;
  float* TV   = ws + O_TV;
  float* C0p  = ws + O_C0;
  float* C1p  = ws + O_C1;
  float* A0p  = ws + O_A0;
  float* A1p  = ws + O_A1;
  float* PART = ws + O_PART;

  build_wcat<<<(600 * 1024 + 255) / 256, 256, 0, stream>>>(cw1, cw2, cw3, WCAT);
  launch_gemm(stream, emb, WCAT, nullptr, nullptr, PROJ,
              VOC_, 600, TCE_, TCE_, 1, TCE_, 1, 600, 0,
              1, 1, 0,0,0,0,0,0, 1.f, 0);
  feats_k<<<B_ * SEQ_, 320, 0, stream>>>(PROJ, src, cb1, cb2, cb3, FEATS, 600);
  launch_gemm(stream, FEATS, tcfw, tcfb, nullptr, XLN,
              B_ * SEQ_, E_, 300, 300, 1, 300, 1, E_, 0,
              1, 1, 0,0,0,0,0,0, 1.f, 0);
  ln_k<<<B_ * SEQ_, 256, 0, stream>>>(XLN, 0, 1, nullptr, nullptr, 0,
                                      XLN, nullptr, nullptr, nullptr, nullptr,
                                      nullptr, nullptr, SEQ_);
  build_x1<<<(3232 * 512 + 255) / 256, 256, 0, stream>>>(XLN, X1);

  auto encoder = [&](float* X, int S, int R){
    for (int l = 0; l < L_; ++l) {
      const float* Wq_l = Wq + (long long)l * E_ * E_;
      const float* Wk_l = Wk + (long long)l * E_ * E_;
      const float* Wv_l = Wv + (long long)l * E_ * E_;
      const float* Wo_l = Wo + (long long)l * E_ * E_;
      const float* W1_l = W1 + (long long)l * NHID_ * E_;
      const float* W2_l = W2 + (long long)l * E_ * NHID_;
      const float* bq_l = bq + l * E_;  const float* bk_l = bk + l * E_;
      const float* bv_l = bv + l * E_;  const float* bo_l = bo + l * E_;
      const float* b1_l = b1v + l * NHID_; const float* b2_l = b2v + l * E_;
      const float* g1_l = g1 + l * E_;  const float* be1_l = be1 + l * E_;
      const float* g2_l = g2 + l * E_;  const float* be2_l = be2 + l * E_;

      launch_gemm(stream, X, Wq_l, bq_l, nullptr, XQ, R, E_, E_,
                  E_, 1, E_, 1, E_, 0, 1, 1, 0,0,0,0,0,0, 1.f, 0);
      launch_gemm(stream, X, Wk_l, bk_l, nullptr, XK, R, E_, E_,
                  E_, 1, E_, 1, E_, 0, 1, 1, 0,0,0,0,0,0, 1.f, 0);
      launch_gemm(stream, X, Wv_l, bv_l, nullptr, XV, R, E_, E_,
                  E_, 1, E_, 1, E_, 0, 1, 1, 0,0,0,0,0,0, 1.f, 0);
      launch_gemm(stream, XQ, XK, nullptr, nullptr, BIG, S, S, DH_,
                  E_, 1, E_, 1, S, 0,
                  B_ * H_, H_,
                  (long long)S * E_, DH_, (long long)S * E_, DH_,
                  (long long)H_ * S * S, (long long)S * S,
                  0.125f, 0);
      attn_softmax<<<B_ * H_ * S, 256, 0, stream>>>(BIG, S);
      launch_gemm(stream, BIG, XV, nullptr, nullptr, CTX, S, DH_, S,
                  S, 1, 1, E_, E_, 0,
                  B_ * H_, H_,
                  (long long)H_ * S * S, (long long)S * S,
                  (long long)S * E_, DH_,
                  (long long)S * E_, DH_,
                  1.f, 0);
      launch_gemm(stream, CTX, Wo_l, bo_l, X, TMP, R, E_, E_,
                  E_, 1, E_, 1, E_, E_, 1, 1, 0,0,0,0,0,0, 1.f, 0);
      ln_k<<<R, 256, 0, stream>>>(TMP, 0, 1, nullptr, nullptr, 0,
                                  X, g1_l, be1_l, nullptr, nullptr, nullptr, nullptr, S);
      launch_gemm(stream, X, W1_l, b1_l, nullptr, BIG, R, NHID_, E_,
                  E_, 1, E_, 1, NHID_, 0, 1, 1, 0,0,0,0,0,0, 1.f, 1);
      launch_gemm(stream, BIG, W2_l, b2_l, X, TMP, R, E_, NHID_,
                  NHID_, 1, NHID_, 1, E_, E_, 1, 1, 0,0,0,0,0,0, 1.f, 0);
      ln_k<<<R, 256, 0, stream>>>(TMP, 0, 1, nullptr, nullptr, 0,
                                  X, g2_l, be2_l, nullptr, nullptr, nullptr, nullptr, S);
    }
  };

  auto post = [&](float* X, int S, int R, float* H1v, float* ALLPf, float* PREDf){
    launch_gemm(stream, X, fc1w, fc1b, nullptr, H1v, R, E_, E_,
                E_, 1, E_, 1, E_, 0, 1, 1, 0,0,0,0,0,0, 1.f, 2);
    ln_k<<<R, 256, 0, stream>>>(H1v, 0, 1, nullptr, nullptr, 0,
                                ALLPf, nullptr, nullptr, nullptr, nullptr, pscale, pbias, S);
    launch_gemm(stream, ALLPf, fc2w, fc2b, nullptr, PREDf, R, 200, E_,
                E_, 1, E_, 1, 200, 0, 1, 1, 0,0,0,0,0,0, 1.f, 0);
  };

  encoder(X1, 101, B_ * 101);
  post(X1, 101, B_ * 101, XQ, XK, CTX);
  copy_cls<<<(B_ * 200 + 255) / 256, 256, 0, stream>>>(CTX, CLS);
  softmax_rows<<<B_, 256, 0, stream>>>(CLS, out + 6400, 200);
  softmax_rows<<<200, 256, 0, stream>>>(lab, LSOFT, 200);
  launch_gemm(stream, CTX + 200, fc3w, fc3b, nullptr, TMP, 200, 200, 100,
              1, 200, 100, 1, 200, 0,
              B_, 1, 101LL * 200, 0, 0, 0, 200LL * 200, 0, 1.f, 0);
  tokvec_k<<<B_ * 200, 256, 0, stream>>>(LSOFT, TMP, CLS, TV);
  softmax_rows<<<B_, 256, 0, stream>>>(TV, out, 200);

  encoder(XLN, SEQ_, B_ * SEQ_);
  post(XLN, SEQ_, B_ * SEQ_, XQ, XK, CTX);
  {
    dim3 g(B_, 4);
    seg_soft_k<<<g, 256, 0, stream>>>(CTX, XK, C0p, C1p, A0p, A1p);
  }
  loss_partial_k<<<B_, 256, 0, stream>>>(C0p, C1p, A0p, A1p, PART);
  loss_final_k<<<1, 64, 0, stream>>>(PART, out + 12800);
}

// Round 7
// 3844.867 us; speedup vs baseline: 1.9082x; 1.9082x over previous
//
#include <hip/hip_runtime.h>
#include <float.h>
#include <math.h>

// ---------------------------------------------------------------------------
// CoKE model. Round 7: revert dbuf (back to 32KB single-buffer staging —
// occupancy > intra-block prefetch), keep split-K + fused reductions in ln_k.
// B=32 SEQ=200 TOK=50 E=512 H=8 DH=64 NHID=2048 L=6 VOC=12525 TC_EMB=1024
// ---------------------------------------------------------------------------

#define B_   32
#define SEQ_ 200
#define TOK_ 50
#define E_   512
#define H_   8
#define DH_  64
#define NHID_ 2048
#define L_   6
#define VOC_ 12525
#define TCE_ 1024

typedef unsigned short ushort_t;
typedef __attribute__((ext_vector_type(8))) short bf16x8;
typedef __attribute__((ext_vector_type(4))) float f32x4;
typedef __attribute__((address_space(1))) const unsigned int GU32;
typedef __attribute__((address_space(3))) unsigned int LU32;

// ------------------------- helpers -----------------------------------------
__device__ __forceinline__ unsigned short f2bf(float x){
  unsigned u = __float_as_uint(x);
  unsigned r = u + 0x7fff + ((u >> 16) & 1);
  return (unsigned short)(r >> 16);
}
__device__ __forceinline__ float bf2f(unsigned short h){
  return __uint_as_float(((unsigned)h) << 16);
}

__device__ __forceinline__ float waveReduceSum(float v){
#pragma unroll
  for (int o = 32; o > 0; o >>= 1) v += __shfl_down(v, o, 64);
  return v;
}
__device__ __forceinline__ float waveReduceMax(float v){
#pragma unroll
  for (int o = 32; o > 0; o >>= 1) v = fmaxf(v, __shfl_down(v, o, 64));
  return v;
}
__device__ __forceinline__ float blockReduceSum256(float v, float* sm){
  v = waveReduceSum(v);
  int lane = threadIdx.x & 63, w = threadIdx.x >> 6;
  __syncthreads();
  if (lane == 0) sm[w] = v;
  __syncthreads();
  return sm[0] + sm[1] + sm[2] + sm[3];
}
__device__ __forceinline__ float blockReduceMax256(float v, float* sm){
  v = waveReduceMax(v);
  int lane = threadIdx.x & 63, w = threadIdx.x >> 6;
  __syncthreads();
  if (lane == 0) sm[w] = v;
  __syncthreads();
  return fmaxf(fmaxf(sm[0], sm[1]), fmaxf(sm[2], sm[3]));
}

// ------------------------- generic fp32 strided batched GEMM ---------------
__global__ __launch_bounds__(256) void gemm_k(
    const float* __restrict__ A, const float* __restrict__ B,
    const float* __restrict__ bias, const float* __restrict__ Res,
    float* __restrict__ C,
    int M, int N, int K,
    long long sAm, long long sAk, long long sBn, long long sBk,
    long long sCm, long long sRm,
    int Hd,
    long long bAb, long long bAh, long long bBb, long long bBh,
    long long bCb, long long bCh,
    float alpha, int epi)
{
  __shared__ float As[16][68];
  __shared__ float Bs[16][68];
  int z = blockIdx.z;
  int zb = z / Hd, zh = z - zb * Hd;
  A += (long long)zb * bAb + (long long)zh * bAh;
  B += (long long)zb * bBb + (long long)zh * bBh;
  C += (long long)zb * bCb + (long long)zh * bCh;
  int m0 = blockIdx.y * 64, n0 = blockIdx.x * 64;
  int tid = threadIdx.y * 16 + threadIdx.x;
  float acc[4][4] = {};
  for (int k0 = 0; k0 < K; k0 += 16) {
#pragma unroll
    for (int i = 0; i < 4; ++i) {
      int idx = tid + 256 * i;
      int kk = idx & 15, mm = idx >> 4;
      int m = m0 + mm, k = k0 + kk;
      As[kk][mm] = (m < M && k < K) ? A[(long long)m * sAm + (long long)k * sAk] : 0.f;
      int n = n0 + mm;
      Bs[kk][mm] = (n < N && k < K) ? B[(long long)n * sBn + (long long)k * sBk] : 0.f;
    }
    __syncthreads();
#pragma unroll
    for (int kk = 0; kk < 16; ++kk) {
      float a[4], b[4];
#pragma unroll
      for (int i = 0; i < 4; ++i) a[i] = As[kk][threadIdx.y * 4 + i];
#pragma unroll
      for (int j = 0; j < 4; ++j) b[j] = Bs[kk][threadIdx.x * 4 + j];
#pragma unroll
      for (int i = 0; i < 4; ++i)
#pragma unroll
        for (int j = 0; j < 4; ++j) acc[i][j] = fmaf(a[i], b[j], acc[i][j]);
    }
    __syncthreads();
  }
#pragma unroll
  for (int i = 0; i < 4; ++i) {
    int m = m0 + threadIdx.y * 4 + i;
    if (m >= M) continue;
#pragma unroll
    for (int j = 0; j < 4; ++j) {
      int n = n0 + threadIdx.x * 4 + j;
      if (n >= N) continue;
      float v = acc[i][j] * alpha;
      if (bias) v += bias[n];
      if (epi == 1) v = fmaxf(v, 0.f);
      else if (epi == 2) v = 0.5f * v * (1.f + erff(v * 0.70710678f));
      if (Res) v += Res[(long long)m * sRm + n];
      C[(long long)m * sCm + n] = v;
    }
  }
}

static inline void launch_gemm(hipStream_t st,
    const float* A, const float* B, const float* bias, const float* Res, float* C,
    int M, int N, int K,
    long long sAm, long long sAk, long long sBn, long long sBk,
    long long sCm, long long sRm,
    int nz, int Hd,
    long long bAb, long long bAh, long long bBb, long long bBh,
    long long bCb, long long bCh,
    float alpha, int epi)
{
  dim3 g((N + 63) / 64, (M + 63) / 64, nz), bl(16, 16);
  gemm_k<<<g, bl, 0, st>>>(A, B, bias, Res, C, M, N, K,
                           sAm, sAk, sBn, sBk, sCm, sRm, Hd,
                           bAb, bAh, bBb, bBh, bCb, bCh, alpha, epi);
}

// ------------------------- bf16x3 MFMA GEMM (XCD swizzle + splitK) ---------
// C = A @ B^T (+bias/epi/Res when nsplit==1). nsplit>1: raw fp32 partials to
// Cf + sp*splitStride (reduced later in ln_k / add2 kernel).
// 128x128 tile, 4 waves, BK=32, single 32KB LDS buffer (occupancy-friendly).
__global__ __launch_bounds__(256) void mgemm_k(
    const ushort_t* __restrict__ Ah, const ushort_t* __restrict__ Al,
    const ushort_t* __restrict__ Bh, const ushort_t* __restrict__ Bl,
    const float* __restrict__ bias, const float* __restrict__ Res,
    float* __restrict__ Cf, ushort_t* __restrict__ Chh, ushort_t* __restrict__ Cll,
    int M, int N, int K, int epi, int Mslice, int Nt, int nsplit,
    int kstepsPer, long long splitStride)
{
  __shared__ __align__(16) ushort_t smem[4][128 * 32];
  int lin = blockIdx.x;
  int xcd = lin & 7;
  int q = lin >> 3;
  int ml = q % Mslice;
  int q2 = q / Mslice;
  int nt = q2 % Nt;
  int sp = q2 / Nt;
  int mt = xcd * Mslice + ml;
  if (mt * 128 >= M) return;
  int m0 = mt * 128, n0 = nt * 128;
  int kbase = sp * kstepsPer;
  int tid = threadIdx.x;
  int lane = tid & 63, wv = tid >> 6;
  int wm = (wv >> 1) * 64, wn = (wv & 1) * 64;
  int fr = lane & 15, fq = lane >> 4;
  f32x4 acc[4][4];
  f32x4 zero = {0.f, 0.f, 0.f, 0.f};
#pragma unroll
  for (int i = 0; i < 4; ++i)
#pragma unroll
    for (int j = 0; j < 4; ++j) acc[i][j] = zero;

  for (int ks = 0; ks < kstepsPer; ++ks) {
    int k0 = (kbase + ks) << 5;
#pragma unroll
    for (int it = 0; it < 8; ++it) {
      int c = tid + it * 256;            // buf uniform per wave (256-aligned)
      int buf = c >> 9;
      int cc = c & 511;
      int row = cc >> 2, cb = (cc & 3) * 8;
      const ushort_t* gsrc;
      long long grow;
      if (buf < 2) { int ar = m0 + row; if (ar >= M) ar = M - 1; grow = ar;
                     gsrc = buf ? Al : Ah; }
      else         { int br = n0 + row; if (br >= N) br = N - 1; grow = br;
                     gsrc = (buf == 2) ? Bh : Bl; }
      __builtin_amdgcn_global_load_lds((GU32*)(gsrc + grow * K + k0 + cb),
                                       (LU32*)(&smem[buf][0] + cc * 8), 16, 0, 0);
    }
    __syncthreads();
    bf16x8 ah[4], al[4], bh8[4], bl8[4];
#pragma unroll
    for (int i = 0; i < 4; ++i) {
      ah[i]  = *(const bf16x8*)(&smem[0][0] + (wm + i * 16 + fr) * 32 + fq * 8);
      al[i]  = *(const bf16x8*)(&smem[1][0] + (wm + i * 16 + fr) * 32 + fq * 8);
      bh8[i] = *(const bf16x8*)(&smem[2][0] + (wn + i * 16 + fr) * 32 + fq * 8);
      bl8[i] = *(const bf16x8*)(&smem[3][0] + (wn + i * 16 + fr) * 32 + fq * 8);
    }
#pragma unroll
    for (int i = 0; i < 4; ++i)
#pragma unroll
      for (int j = 0; j < 4; ++j) {
        acc[i][j] = __builtin_amdgcn_mfma_f32_16x16x32_bf16(ah[i], bh8[j], acc[i][j], 0, 0, 0);
        acc[i][j] = __builtin_amdgcn_mfma_f32_16x16x32_bf16(ah[i], bl8[j], acc[i][j], 0, 0, 0);
        acc[i][j] = __builtin_amdgcn_mfma_f32_16x16x32_bf16(al[i], bh8[j], acc[i][j], 0, 0, 0);
      }
    __syncthreads();
  }

  if (nsplit > 1) {
    float* Cs = Cf + (long long)sp * splitStride;
#pragma unroll
    for (int i = 0; i < 4; ++i)
#pragma unroll
      for (int j = 0; j < 4; ++j) {
        int col = n0 + wn + j * 16 + fr;
        if (col >= N) continue;
#pragma unroll
        for (int r = 0; r < 4; ++r) {
          int row = m0 + wm + i * 16 + fq * 4 + r;
          if (row >= M) continue;
          Cs[(long long)row * N + col] = acc[i][j][r];
        }
      }
    return;
  }
#pragma unroll
  for (int i = 0; i < 4; ++i) {
#pragma unroll
    for (int j = 0; j < 4; ++j) {
      int col = n0 + wn + j * 16 + fr;
      if (col >= N) continue;
#pragma unroll
      for (int r = 0; r < 4; ++r) {
        int row = m0 + wm + i * 16 + fq * 4 + r;
        if (row >= M) continue;
        float v = acc[i][j][r];
        if (bias) v += bias[col];
        if (epi == 1) v = fmaxf(v, 0.f);
        else if (epi == 2) v = 0.5f * v * (1.f + erff(v * 0.70710678f));
        long long idx = (long long)row * N + col;
        if (Res) v += Res[idx];
        if (Cf) Cf[idx] = v;
        if (Chh) {
          unsigned short h = f2bf(v);
          Chh[idx] = h;
          Cll[idx] = f2bf(v - bf2f(h));
        }
      }
    }
  }
}

// PRED = s0 + s1 + bias[col]
__global__ void add_bias2_k(const float* __restrict__ s0, const float* __restrict__ s1,
                            const float* __restrict__ bias, float* __restrict__ o,
                            int total, int N){
  int idx = blockIdx.x * 256 + threadIdx.x;
  if (idx >= total) return;
  o[idx] = s0[idx] + s1[idx] + bias[idx % N];
}

// ------------------------- attention kernels -------------------------------
#define BND_ROWS 64
#define BND_STAGE 73
__global__ __launch_bounds__(256) void attn_band(
    const float* __restrict__ QKV,
    ushort_t* __restrict__ oh, ushort_t* __restrict__ ol, int S, int nrb)
{
  __shared__ float Kl[BND_STAGE][68];
  __shared__ float Vl[BND_STAGE][68];
  __shared__ float Ql[BND_ROWS][68];
  __shared__ float sc[BND_ROWS][12];
  int bh = blockIdx.x / nrb, rblk = blockIdx.x % nrb;
  int b = bh / 6, h = bh % 6;
  int r0 = 1 + rblk * BND_ROWS;
  int nrows = S - r0; if (nrows > BND_ROWS) nrows = BND_ROWS;
  int lo0 = r0 - 5; if (lo0 < 0) lo0 = 0;
  int hi0 = r0 + nrows - 1 + 4; if (hi0 > S - 1) hi0 = S - 1;
  int cnt = hi0 - lo0 + 1;
  int t = threadIdx.x;
  const float* base = QKV + ((long long)(b * S + lo0)) * 1536 + h * 64;
  for (int idx = t; idx < cnt * 64; idx += 256) {
    int row = idx >> 6, d = idx & 63;
    Kl[row][d] = base[(long long)row * 1536 + 512 + d];
    Vl[row][d] = base[(long long)row * 1536 + 1024 + d];
  }
  const float* qbase = QKV + ((long long)(b * S + r0)) * 1536 + h * 64;
  for (int idx = t; idx < nrows * 64; idx += 256) {
    int row = idx >> 6, d = idx & 63;
    Ql[row][d] = qbase[(long long)row * 1536 + d];
  }
  __syncthreads();
  for (int p = t; p < nrows * 10; p += 256) {
    int ri = p / 10, jo = p - ri * 10;
    int r = r0 + ri;
    int lo = r - 5; if (lo < 0) lo = 0;
    int hi = r + 4; if (hi > S - 1) hi = S - 1;
    int j = lo + jo;
    float s;
    if (j > hi) s = -FLT_MAX;
    else {
      int jl = j - lo0;
      float a = 0.f;
      const float4* qv = (const float4*)&Ql[ri][0];
      const float4* kv = (const float4*)&Kl[jl][0];
#pragma unroll
      for (int c = 0; c < 16; ++c) {
        float4 x = qv[c], y = kv[c];
        a += x.x * y.x + x.y * y.y + x.z * y.z + x.w * y.w;
      }
      s = a * 0.125f;
    }
    sc[ri][jo] = s;
  }
  __syncthreads();
  if (t < nrows) {
    float mx = -FLT_MAX;
#pragma unroll
    for (int jo = 0; jo < 10; ++jo) mx = fmaxf(mx, sc[t][jo]);
    float pv[10]; float sum = 0.f;
#pragma unroll
    for (int jo = 0; jo < 10; ++jo) {
      float s = sc[t][jo];
      float e = (s == -FLT_MAX) ? 0.f : expf(s - mx);
      pv[jo] = e; sum += e;
    }
    float inv = 1.f / sum;
#pragma unroll
    for (int jo = 0; jo < 10; ++jo) sc[t][jo] = pv[jo] * inv;
  }
  __syncthreads();
  for (int idx = t; idx < nrows * 64; idx += 256) {
    int ri = idx >> 6, d = idx & 63;
    int r = r0 + ri;
    int lo = r - 5; if (lo < 0) lo = 0;
    int jbase = lo - lo0;
    float a = 0.f;
#pragma unroll
    for (int jo = 0; jo < 10; ++jo) {
      int jl = jbase + jo; if (jl >= cnt) jl = cnt - 1;
      a += sc[ri][jo] * Vl[jl][d];
    }
    long long o = ((long long)(b * S + r)) * 512 + h * 64 + d;
    unsigned short hh = f2bf(a);
    oh[o] = hh; ol[o] = f2bf(a - bf2f(hh));
  }
}

__global__ __launch_bounds__(256) void attn_full(
    const float* __restrict__ QKV,
    ushort_t* __restrict__ oh, ushort_t* __restrict__ ol, int S)
{
  __shared__ float sm_m[4], sm_l[4], sm_acc[4][64];
  int idx = blockIdx.x;
  int b, h, i;
  if (idx < B_ * H_) { b = idx >> 3; h = idx & 7; i = 0; }
  else { int r = idx - B_ * H_; h = 6 + r / (S - 1); i = 1 + r % (S - 1); b = 0; }
  int t = threadIdx.x, lane = t & 63, w = t >> 6;
  const float* Qr = QKV + ((long long)(b * S + i)) * 1536 + h * 64;
  const float* Kb = QKV + ((long long)(b * S)) * 1536 + 512 + h * 64;
  const float* Vb = QKV + ((long long)(b * S)) * 1536 + 1024 + h * 64;
  float q = Qr[lane];
  float m = -FLT_MAX, l = 0.f, acc = 0.f;
  for (int j0 = w * 4; j0 < S; j0 += 16) {
    float s[4];
#pragma unroll
    for (int c = 0; c < 4; ++c) {
      int j = j0 + c;
      float kv = (j < S) ? Kb[(long long)j * 1536 + lane] : 0.f;
      float r = waveReduceSum(q * kv);
      s[c] = r * 0.125f;
    }
#pragma unroll
    for (int c = 0; c < 4; ++c) {
      s[c] = __shfl(s[c], 0);
      if (j0 + c >= S) s[c] = -FLT_MAX;
    }
    float mc = fmaxf(fmaxf(s[0], s[1]), fmaxf(s[2], s[3]));
    float mn = fmaxf(m, mc);
    float scale = (m == -FLT_MAX) ? 0.f : expf(m - mn);
    float lsum = 0.f, vsum = 0.f;
#pragma unroll
    for (int c = 0; c < 4; ++c) {
      int j = j0 + c;
      if (j < S) {
        float p = expf(s[c] - mn);
        lsum += p;
        vsum += p * Vb[(long long)j * 1536 + lane];
      }
    }
    acc = acc * scale + vsum;
    l = l * scale + lsum;
    m = mn;
  }
  sm_m[w] = m;
  sm_l[w] = l;
  sm_acc[w][lane] = acc;
  __syncthreads();
  if (t < 64) {
    float M = fmaxf(fmaxf(sm_m[0], sm_m[1]), fmaxf(sm_m[2], sm_m[3]));
    float L = 0.f, A = 0.f;
#pragma unroll
    for (int w2 = 0; w2 < 4; ++w2) {
      float e = (sm_m[w2] == -FLT_MAX) ? 0.f : expf(sm_m[w2] - M);
      L += sm_l[w2] * e;
      A += sm_acc[w2][t] * e;
    }
    float ctx = A / L;
    long long o = ((long long)(b * S + i)) * 512 + h * 64 + t;
    unsigned short hh = f2bf(ctx);
    oh[o] = hh; ol[o] = f2bf(ctx - bf2f(hh));
  }
}

__global__ __launch_bounds__(256) void attn_unif(
    const float* __restrict__ QKV,
    ushort_t* __restrict__ oh, ushort_t* __restrict__ ol, int S)
{
  __shared__ float part[4][64];
  __shared__ float vm[64];
  int blk = blockIdx.x;
  int b = 1 + (blk >> 1), h = 6 + (blk & 1);
  int t = threadIdx.x, lane = t & 63, w = t >> 6;
  const float* Vb = QKV + ((long long)(b * S)) * 1536 + 1024 + h * 64;
  float s = 0.f;
  for (int j = w; j < S; j += 4) s += Vb[(long long)j * 1536 + lane];
  part[w][lane] = s;
  __syncthreads();
  if (t < 64) vm[t] = (part[0][t] + part[1][t] + part[2][t] + part[3][t]) * (1.f / S);
  __syncthreads();
  float m = vm[lane];
  unsigned short hh = f2bf(m);
  unsigned short hl = f2bf(m - bf2f(hh));
  for (int i = 1 + w; i < S; i += 4) {
    long long o = ((long long)(b * S + i)) * 512 + h * 64 + lane;
    oh[o] = hh; ol[o] = hl;
  }
}

// ------------------------- conversion kernels ------------------------------
__global__ void conv_hl(const float* __restrict__ x, ushort_t* __restrict__ h,
                        ushort_t* __restrict__ l, long long n){
  long long i = (long long)blockIdx.x * 256 + threadIdx.x;
  if (i >= n) return;
  float v = x[i];
  unsigned short hh = f2bf(v);
  h[i] = hh;
  l[i] = f2bf(v - bf2f(hh));
}

__global__ void conv_qkv(const float* __restrict__ Wq, const float* __restrict__ Wk,
                         const float* __restrict__ Wv,
                         ushort_t* __restrict__ h, ushort_t* __restrict__ l){
  int idx = blockIdx.x * 256 + threadIdx.x;
  if (idx >= L_ * 1536 * 512) return;
  int li = idx / (1536 * 512);
  int r = (idx / 512) % 1536;
  int c = idx & 511;
  const float* W = (r < 512) ? Wq : (r < 1024) ? Wk : Wv;
  int rr = r & 511;
  float v = W[(long long)li * 262144 + rr * 512 + c];
  unsigned short hh = f2bf(v);
  h[idx] = hh;
  l[idx] = f2bf(v - bf2f(hh));
}

__global__ void pack_bqkv(const float* __restrict__ bq, const float* __restrict__ bk,
                          const float* __restrict__ bv, float* __restrict__ o){
  int idx = blockIdx.x * 256 + threadIdx.x;
  if (idx >= L_ * 1536) return;
  int l = idx / 1536, r = idx % 1536;
  o[idx] = (r < 512) ? bq[l * 512 + r] : (r < 1024) ? bk[l * 512 + r - 512]
                                                    : bv[l * 512 + r - 1024];
}

__global__ void build_tcfw_hl(const float* __restrict__ w,
                              ushort_t* __restrict__ h, ushort_t* __restrict__ l){
  int idx = blockIdx.x * 256 + threadIdx.x;
  if (idx >= 512 * 320) return;
  int r = idx / 320, c = idx - r * 320;
  float v = (c < 300) ? w[r * 300 + c] : 0.f;
  unsigned short hh = f2bf(v);
  h[idx] = hh;
  l[idx] = f2bf(v - bf2f(hh));
}

// ------------------------- small kernels -----------------------------------
__global__ void build_wcat(const float* __restrict__ cw1, const float* __restrict__ cw2,
                           const float* __restrict__ cw3, float* __restrict__ w){
  int idx = blockIdx.x * 256 + threadIdx.x;
  if (idx >= 600 * 1024) return;
  int o = idx >> 10, c = idx & 1023;
  float v;
  if      (o < 100) v = cw1[o * 1024 + c];
  else if (o < 200) v = cw2[(o - 100) * 2048 + c];
  else if (o < 300) v = cw2[(o - 200) * 2048 + 1024 + c];
  else if (o < 400) v = cw3[(o - 300) * 3072 + c];
  else if (o < 500) v = cw3[(o - 400) * 3072 + 1024 + c];
  else              v = cw3[(o - 500) * 3072 + 2048 + c];
  w[idx] = v;
}

__global__ void build_wcat_hl(const float* __restrict__ cw1, const float* __restrict__ cw2,
                              const float* __restrict__ cw3,
                              ushort_t* __restrict__ wh, ushort_t* __restrict__ wl){
  int idx = blockIdx.x * 256 + threadIdx.x;
  if (idx >= 640 * 1024) return;
  int o = idx >> 10, c = idx & 1023;
  float v = 0.f;
  if      (o < 100) v = cw1[o * 1024 + c];
  else if (o < 200) v = cw2[(o - 100) * 2048 + c];
  else if (o < 300) v = cw2[(o - 200) * 2048 + 1024 + c];
  else if (o < 400) v = cw3[(o - 300) * 3072 + c];
  else if (o < 500) v = cw3[(o - 400) * 3072 + 1024 + c];
  else if (o < 600) v = cw3[(o - 500) * 3072 + 2048 + c];
  unsigned short h = f2bf(v);
  wh[idx] = h;
  wl[idx] = f2bf(v - bf2f(h));
}

__global__ void feats_k(const float* __restrict__ proj, const int* __restrict__ src,
                        const float* __restrict__ cb1, const float* __restrict__ cb2,
                        const float* __restrict__ cb3, float* __restrict__ feats, int ld){
  __shared__ int ids[TOK_];
  int n = blockIdx.x;
  int t = threadIdx.x;
  if (t < TOK_) ids[t] = src[n * TOK_ + t];
  __syncthreads();
  if (t >= 300) return;
  float bia, m = -FLT_MAX;
  if (t < 100) {
    bia = cb1[t];
    for (int k = 0; k < 50; ++k)
      m = fmaxf(m, proj[(long long)ids[k] * ld + t]);
  } else if (t < 200) {
    int o = t - 100; bia = cb2[o];
    for (int k = 0; k < 49; ++k)
      m = fmaxf(m, proj[(long long)ids[k] * ld + 100 + o] +
                   proj[(long long)ids[k + 1] * ld + 200 + o]);
  } else {
    int o = t - 200; bia = cb3[o];
    for (int k = 0; k < 48; ++k)
      m = fmaxf(m, proj[(long long)ids[k] * ld + 300 + o] +
                   proj[(long long)ids[k + 1] * ld + 400 + o] +
                   proj[(long long)ids[k + 2] * ld + 500 + o]);
  }
  feats[(long long)n * 300 + t] = fmaxf(m + bia, 0.f);
}

__global__ void feats_hl_k(const float* __restrict__ proj, const int* __restrict__ src,
                           const float* __restrict__ cb1, const float* __restrict__ cb2,
                           const float* __restrict__ cb3,
                           ushort_t* __restrict__ fh, ushort_t* __restrict__ fl, int ld){
  __shared__ int ids[TOK_];
  int n = blockIdx.x;
  int t = threadIdx.x;               // 320 threads
  if (t < TOK_) ids[t] = src[n * TOK_ + t];
  __syncthreads();
  float a = 0.f;
  if (t < 300) {
    float bia, m = -FLT_MAX;
    if (t < 100) {
      bia = cb1[t];
      for (int k = 0; k < 50; ++k)
        m = fmaxf(m, proj[(long long)ids[k] * ld + t]);
    } else if (t < 200) {
      int o = t - 100; bia = cb2[o];
      for (int k = 0; k < 49; ++k)
        m = fmaxf(m, proj[(long long)ids[k] * ld + 100 + o] +
                     proj[(long long)ids[k + 1] * ld + 200 + o]);
    } else {
      int o = t - 200; bia = cb3[o];
      for (int k = 0; k < 48; ++k)
        m = fmaxf(m, proj[(long long)ids[k] * ld + 300 + o] +
                     proj[(long long)ids[k + 1] * ld + 400 + o] +
                     proj[(long long)ids[k + 2] * ld + 500 + o]);
    }
    a = fmaxf(m + bia, 0.f);
  }
  long long o = (long long)n * 320 + t;
  unsigned short hh = f2bf(a);
  fh[o] = hh;
  fl[o] = f2bf(a - bf2f(hh));
}

// LayerNorm. Input = sum of nsplit slices (stride sstr) + bias2, then epi2
// (0 none / 1 relu / 2 gelu), then +res2, then LN (+affine/post), fp32 out,
// optional bf16 hi/lo pair out.
__global__ __launch_bounds__(256) void ln_k(
    const float* __restrict__ in, long long sstr, int nsplit,
    const float* __restrict__ bias2, const float* __restrict__ res2, int epi2,
    float* __restrict__ out, const float* __restrict__ g, const float* __restrict__ bta,
    ushort_t* __restrict__ oh, ushort_t* __restrict__ ol,
    const float* __restrict__ pscale, const float* __restrict__ pbias, int S)
{
  __shared__ float sm[4];
  long long row = blockIdx.x;
  int t = threadIdx.x;
  const float* x = in + row * E_;
  float v0 = x[t], v1 = x[t + 256];
  for (int s = 1; s < nsplit; ++s) {
    v0 += x[(long long)s * sstr + t];
    v1 += x[(long long)s * sstr + t + 256];
  }
  if (bias2) { v0 += bias2[t]; v1 += bias2[t + 256]; }
  if (epi2 == 1) { v0 = fmaxf(v0, 0.f); v1 = fmaxf(v1, 0.f); }
  else if (epi2 == 2) {
    v0 = 0.5f * v0 * (1.f + erff(v0 * 0.70710678f));
    v1 = 0.5f * v1 * (1.f + erff(v1 * 0.70710678f));
  }
  if (res2) { v0 += res2[row * E_ + t]; v1 += res2[row * E_ + t + 256]; }
  float* y = out + row * E_;
  float mu = blockReduceSum256(v0 + v1, sm) * (1.f / E_);
  float d0 = v0 - mu, d1 = v1 - mu;
  float var = blockReduceSum256(d0 * d0 + d1 * d1, sm) * (1.f / E_);
  float r = rsqrtf(var + 1e-12f);
  float o0 = d0 * r, o1 = d1 * r;
  if (g) { o0 = o0 * g[t] + bta[t]; o1 = o1 * g[t + 256] + bta[t + 256]; }
  if (pscale) {
    long long b = row / S, s = row % S;
    long long off = (b * 300 + s) * E_;
    o0 = o0 * pscale[off + t] + pbias[off + t];
    o1 = o1 * pscale[off + t + 256] + pbias[off + t + 256];
  }
  y[t] = o0; y[t + 256] = o1;
  if (oh) {
    unsigned short h0 = f2bf(o0), h1 = f2bf(o1);
    oh[row * E_ + t] = h0;       oh[row * E_ + t + 256] = h1;
    ol[row * E_ + t] = f2bf(o0 - bf2f(h0));
    ol[row * E_ + t + 256] = f2bf(o1 - bf2f(h1));
  }
}

__global__ void build_x1(const float* __restrict__ xln, float* __restrict__ x1){
  long long idx = (long long)blockIdx.x * 256 + threadIdx.x;
  if (idx >= 3232LL * 512) return;
  long long row = idx >> 9; int c = (int)(idx & 511);
  long long b = row / 101, s = row % 101;
  x1[idx] = (s == 0) ? 0.f : xln[((b * 200) + (s - 1)) * 512 + c];
}

__global__ __launch_bounds__(256) void attn_softmax(float* __restrict__ sc, int S){
  __shared__ float sm[4];
  long long row = blockIdx.x;
  int i = (int)(row % S); long long bh = row / S;
  int h = (int)(bh & 7); int b = (int)(bh >> 3);
  float* p = sc + row * S;
  int t = threadIdx.x;
  bool inr = t < S;
  bool allow;
  if (i == 0) allow = true;
  else if (h < 6) allow = (t >= i - 5) && (t <= i + 4);
  else allow = (b == 0);
  float v = inr ? (allow ? p[t] : -1e9f) : -FLT_MAX;
  float mx = blockReduceMax256(v, sm);
  float e = inr ? expf(v - mx) : 0.f;
  float s = blockReduceSum256(e, sm);
  if (inr) p[t] = e / s;
}

__global__ __launch_bounds__(256) void softmax_rows(const float* __restrict__ in,
                                                    float* __restrict__ out, int n){
  __shared__ float sm[4];
  long long row = blockIdx.x;
  const float* x = in + row * n;
  float* y = out + row * n;
  int t = threadIdx.x;
  float v0 = (t < n) ? x[t] : -FLT_MAX;
  float v1 = (t + 256 < n) ? x[t + 256] : -FLT_MAX;
  float mx = blockReduceMax256(fmaxf(v0, v1), sm);
  float e0 = (t < n) ? expf(v0 - mx) : 0.f;
  float e1 = (t + 256 < n) ? expf(v1 - mx) : 0.f;
  float s = blockReduceSum256(e0 + e1, sm);
  if (t < n) y[t] = e0 / s;
  if (t + 256 < n) y[t + 256] = e1 / s;
}

__global__ void copy_cls(const float* __restrict__ pred, float* __restrict__ cls){
  int idx = blockIdx.x * 256 + threadIdx.x;
  if (idx >= B_ * 200) return;
  int b = idx / 200, m = idx % 200;
  cls[idx] = pred[(long long)b * 101 * 200 + m];
}

__global__ __launch_bounds__(256) void tokvec_k(const float* __restrict__ lsoft,
                         const float* __restrict__ tokmat,
                         const float* __restrict__ cls, float* __restrict__ tv){
  __shared__ float sm[4];
  int bn = blockIdx.x; int b = bn / 200, n = bn % 200;
  int t = threadIdx.x;
  float s = 0.f;
  if (t < 200)
    s = (lsoft[n * 200 + t] + 0.4f * tokmat[((long long)b * 200 + n) * 200 + t]) * cls[b * 200 + t];
  float tot = blockReduceSum256(s, sm);
  if (t == 0) tv[bn] = tot;
}

__global__ __launch_bounds__(256) void seg_soft_k(const float* __restrict__ pred,
                         const float* __restrict__ allp,
                         float* __restrict__ c0, float* __restrict__ c1,
                         float* __restrict__ a0, float* __restrict__ a1){
  __shared__ float sm[4];
  int b = blockIdx.x, which = blockIdx.y;
  const float* srcp; int C;
  if (which < 2) { srcp = pred; C = 200; } else { srcp = allp; C = 512; }
  int i = which & 1;
  int start = i, cnt = i ? 199 : 100;
  float* dst = (which == 0) ? c0 : (which == 1) ? c1 : (which == 2) ? a0 : a1;
  const float* base = srcp + ((long long)b * 200 + start) * C;
  int t = threadIdx.x;
  float m0 = 0.f, m1 = 0.f;
  for (int r = 0; r < cnt; ++r) {
    if (t < C)       m0 += base[(long long)r * C + t];
    if (t + 256 < C) m1 += base[(long long)r * C + t + 256];
  }
  float inv = 1.f / cnt;
  m0 *= inv; m1 *= inv;
  float v0 = (t < C) ? m0 : -FLT_MAX;
  float v1 = (t + 256 < C) ? m1 : -FLT_MAX;
  float mx = blockReduceMax256(fmaxf(v0, v1), sm);
  float e0 = (t < C) ? expf(v0 - mx) : 0.f;
  float e1 = (t + 256 < C) ? expf(v1 - mx) : 0.f;
  float s = blockReduceSum256(e0 + e1, sm);
  if (t < C)       dst[(long long)b * C + t] = e0 / s;
  if (t + 256 < C) dst[(long long)b * C + t + 256] = e1 / s;
}

__global__ __launch_bounds__(256) void loss_partial_k(const float* __restrict__ c0,
                         const float* __restrict__ c1,
                         const float* __restrict__ a0, const float* __restrict__ a1,
                         float* __restrict__ partial){
  __shared__ float sm[4];
  int b = blockIdx.x, t = threadIdx.x;
  float k01 = 0.f, k10 = 0.f;
  if (t < 200) {
    float x = c0[b * 200 + t] + 1e-6f, y = c1[b * 200 + t] + 1e-6f;
    k01 = x * logf(x / y);
    k10 = y * logf(y / x);
  }
  float K01 = blockReduceSum256(k01, sm);
  float K10 = blockReduceSum256(k10, sm);
  float d0 = a0[b * 512 + t] - a1[b * 512 + t];
  float d1 = a0[b * 512 + t + 256] - a1[b * 512 + t + 256];
  float E2 = blockReduceSum256(d0 * d0 + d1 * d1, sm);
  if (t == 0) {
    float euc = sqrtf(fmaxf(E2, 1e-12f));
    float kv[4] = {0.f, K01 * 10.f, K10 * 10.f, 0.f};
    float ev[4] = {1e-6f, euc, euc, 1e-6f};
    float mk = fmaxf(fmaxf(kv[0], kv[1]), fmaxf(kv[2], kv[3]));
    float me = fmaxf(fmaxf(ev[0], ev[1]), fmaxf(ev[2], ev[3]));
    float sk = 0.f, se = 0.f;
    for (int q = 0; q < 4; ++q) { kv[q] = expf(kv[q] - mk); sk += kv[q];
                                  ev[q] = expf(ev[q] - me); se += ev[q]; }
    float p = 0.f;
    for (int q = 0; q < 4; ++q) {
      float aa = kv[q] / sk + 1e-6f, bb = ev[q] / se + 1e-6f;
      p += aa * logf(aa / bb);
    }
    partial[b] = p;
  }
}

__global__ void loss_final_k(const float* __restrict__ partial, float* __restrict__ out){
  if (threadIdx.x == 0) {
    float s = 0.f;
    for (int b = 0; b < B_; ++b) s += partial[b];
    out[0] = s * (100000.f * 0.2f / B_);
  }
}

// ---------------------------------------------------------------------------
extern "C" void kernel_launch(void* const* d_in, const int* in_sizes, int n_in,
                              void* d_out, int out_size, void* d_ws, size_t ws_size,
                              hipStream_t stream) {
  const int*   src   = (const int*)  d_in[0];
  const float* lab   = (const float*)d_in[1];
  const float* emb   = (const float*)d_in[2];
  const float* cw1   = (const float*)d_in[3];
  const float* cb1   = (const float*)d_in[4];
  const float* cw2   = (const float*)d_in[5];
  const float* cb2   = (const float*)d_in[6];
  const float* cw3   = (const float*)d_in[7];
  const float* cb3   = (const float*)d_in[8];
  const float* tcfw  = (const float*)d_in[9];
  const float* tcfb  = (const float*)d_in[10];
  const float* Wq    = (const float*)d_in[11];
  const float* bq    = (const float*)d_in[12];
  const float* Wk    = (const float*)d_in[13];
  const float* bk    = (const float*)d_in[14];
  const float* Wv    = (const float*)d_in[15];
  const float* bv    = (const float*)d_in[16];
  const float* Wo    = (const float*)d_in[17];
  const float* bo    = (const float*)d_in[18];
  const float* W1    = (const float*)d_in[19];
  const float* b1v   = (const float*)d_in[20];
  const float* W2    = (const float*)d_in[21];
  const float* b2v   = (const float*)d_in[22];
  const float* g1    = (const float*)d_in[23];
  const float* be1   = (const float*)d_in[24];
  const float* g2    = (const float*)d_in[25];
  const float* be2   = (const float*)d_in[26];
  const float* fc1w  = (const float*)d_in[27];
  const float* fc1b  = (const float*)d_in[28];
  const float* fc2w  = (const float*)d_in[29];
  const float* fc2b  = (const float*)d_in[30];
  const float* fc3w  = (const float*)d_in[31];
  const float* fc3b  = (const float*)d_in[32];
  const float* pscale= (const float*)d_in[33];
  const float* pbias = (const float*)d_in[34];
  float* out = (float*)d_out;
  float* ws  = (float*)d_ws;
  ushort_t* wsu = (ushort_t*)d_ws;

  const size_t NEED_MFMA = 215200000ULL;

  if (ws_size >= NEED_MFMA) {
    // =================== MFMA path ===================
    const long long P_EMBH  = 0;
    const long long P_EMBL  = 6412800;
    const long long P_WCATH = 12825600;
    const long long P_WCATL = 13153280;
    const long long P_PROJ  = 13480960;     // 12525*640
    const long long P_FEATS = 21496960;     // FH/FL (ushort) region
    const long long SZW4 = 6LL * 512 * 512;        // 1,572,864
    const long long SZW1 = 6LL * 2048 * 512;       // 6,291,456
    const long long UQKVH = 0;                     // 3*SZW4 (L,1536,512)
    const long long UQKVL = 3 * SZW4;
    const long long UOH = 6 * SZW4, UOL = 7 * SZW4;
    const long long U1H = 8 * SZW4,            U1L = 8 * SZW4 + SZW1;
    const long long U2H = 8 * SZW4 + 2 * SZW1, U2L = 8 * SZW4 + 3 * SZW1;
    const long long UF1H = 8 * SZW4 + 4 * SZW1, UF1L = UF1H + 262144;
    const long long O_BIG  = 19136512;      // 13,107,200 fl (FFN bf16 pair)
    const long long O_XLN  = 32243712;      // 3,276,800
    const long long O_X1   = 35520512;      // 1,654,784
    const long long O_QKV  = 37175296;      // 9,830,400 (QKV fp32 / split slices)
    const long long O_TMP  = 47005696;      // 3,276,800 (slice-3 overflow / ALLP)
    const long long O_XH   = 50282496;      // ushort pair
    const long long O_XL   = 51920896;
    const long long O_SM   = 53559296;
    const long long O_LSOFT= O_SM;
    const long long O_CLS  = O_LSOFT + 40000;
    const long long O_TV   = O_CLS + 6400;
    const long long O_C0   = O_TV + 6400;
    const long long O_C1   = O_C0 + 6400;
    const long long O_A0   = O_C1 + 6400;
    const long long O_A1   = O_A0 + 16384;
    const long long O_PART = O_A1 + 16384;  // 64
    const long long O_BQKV = O_PART + 64;   // 9216
    const long long O_FC2W = O_BQKV + 9216; // 102,400 fl (hi+lo ushort)

    ushort_t* EMBH = (ushort_t*)(ws + P_EMBH);
    ushort_t* EMBL = (ushort_t*)(ws + P_EMBL);
    ushort_t* WCATH= (ushort_t*)(ws + P_WCATH);
    ushort_t* WCATL= (ushort_t*)(ws + P_WCATL);
    float* PROJ = ws + P_PROJ;
    ushort_t* FH = (ushort_t*)(ws + P_FEATS);           // 6400x320
    ushort_t* FL = FH + 6400LL * 320;
    float* BIG  = ws + O_BIG;
    float* XLN  = ws + O_XLN;
    float* X1   = ws + O_X1;
    float* QKV  = ws + O_QKV;      // also SPLIT base (spans into TMP for 4-way)
    float* TMP  = ws + O_TMP;      // also ALLP in post
    ushort_t* TCFWH = (ushort_t*)(ws + O_TMP);          // pre-encoder only
    ushort_t* TCFWL = TCFWH + 512 * 320;
    ushort_t* XH = (ushort_t*)(ws + O_XH);
    ushort_t* XL = (ushort_t*)(ws + O_XL);
    float* LSOFT= ws + O_LSOFT;
    float* CLS  = ws + O_CLS;
    float* TV   = ws + O_TV;
    float* C0p  = ws + O_C0;
    float* C1p  = ws + O_C1;
    float* A0p  = ws + O_A0;
    float* A1p  = ws + O_A1;
    float* PART = ws + O_PART;
    float* BQKV = ws + O_BQKV;
    ushort_t* FC2WH = (ushort_t*)(ws + O_FC2W);
    ushort_t* FC2WL = FC2WH + 200 * 512;
    float* SPLIT = QKV;
    float* ALLP  = TMP;
    float* PRED  = QKV;                        // R x 200 (after slices dead)
    float* FC2S  = QKV + 6553600;              // fc2 split slices (2 x R*200)
    float* TOKMAT= QKV + 3276800;              // B x 200 x 200

    auto mgemm = [&](const ushort_t* Ah, const ushort_t* Al,
                     const ushort_t* Bh, const ushort_t* Bl,
                     const float* bias, const float* Res, float* Cf,
                     ushort_t* Ch, ushort_t* Cl, int M, int N, int K, int epi,
                     int nsplit, long long splitStride){
      int Mt = (M + 127) / 128;
      int Nt = (N + 127) / 128;
      int Mslice = (Mt + 7) / 8;
      int kst = (K / nsplit) >> 5;
      dim3 g(8 * Mslice * Nt * nsplit);
      mgemm_k<<<g, 256, 0, stream>>>(Ah, Al, Bh, Bl, bias, Res, Cf, Ch, Cl,
                                     M, N, K, epi, Mslice, Nt, nsplit, kst, splitStride);
    };

    // ---------------- TextCNN ----------------
    conv_hl<<<(VOC_ * TCE_ + 255) / 256, 256, 0, stream>>>(emb, EMBH, EMBL, (long long)VOC_ * TCE_);
    build_wcat_hl<<<(640 * 1024 + 255) / 256, 256, 0, stream>>>(cw1, cw2, cw3, WCATH, WCATL);
    mgemm(EMBH, EMBL, WCATH, WCATL, nullptr, nullptr, PROJ, nullptr, nullptr,
          VOC_, 640, TCE_, 0, 1, 0);
    feats_hl_k<<<B_ * SEQ_, 320, 0, stream>>>(PROJ, src, cb1, cb2, cb3, FH, FL, 640);
    build_tcfw_hl<<<(512 * 320 + 255) / 256, 256, 0, stream>>>(tcfw, TCFWH, TCFWL);
    // x_all: split-2 raw -> SPLIT (QKV region only), reduce+bias+LN in ln_k
    mgemm(FH, FL, TCFWH, TCFWL, nullptr, nullptr, SPLIT, nullptr, nullptr,
          B_ * SEQ_, E_, 320, 0, 2, 6400LL * 512);
    ln_k<<<B_ * SEQ_, 256, 0, stream>>>(SPLIT, 6400LL * 512, 2, tcfb, nullptr, 0,
                                        XLN, nullptr, nullptr, nullptr, nullptr,
                                        nullptr, nullptr, SEQ_);
    build_x1<<<(3232 * 512 + 255) / 256, 256, 0, stream>>>(XLN, X1);

    // ---------------- weight conversion ----------------
    conv_qkv<<<(L_ * 1536 * 512 + 255) / 256, 256, 0, stream>>>(Wq, Wk, Wv,
                                                                wsu + UQKVH, wsu + UQKVL);
    pack_bqkv<<<(L_ * 1536 + 255) / 256, 256, 0, stream>>>(bq, bk, bv, BQKV);
    conv_hl<<<(int)((SZW4 + 255) / 256), 256, 0, stream>>>(Wo, wsu + UOH, wsu + UOL, SZW4);
    conv_hl<<<(int)((SZW1 + 255) / 256), 256, 0, stream>>>(W1, wsu + U1H, wsu + U1L, SZW1);
    conv_hl<<<(int)((SZW1 + 255) / 256), 256, 0, stream>>>(W2, wsu + U2H, wsu + U2L, SZW1);
    conv_hl<<<(262144 + 255) / 256, 256, 0, stream>>>(fc1w, wsu + UF1H, wsu + UF1L, 262144);
    conv_hl<<<(200 * 512 + 255) / 256, 256, 0, stream>>>(fc2w, FC2WH, FC2WL, 200 * 512);

    // ---------------- encoder ----------------
    auto encoder = [&](float* X, int S, int R){
      ushort_t* BIGH = (ushort_t*)BIG;
      ushort_t* BIGL = BIGH + (long long)R * NHID_;
      int nrb = (S - 1 + BND_ROWS - 1) / BND_ROWS;
      int nfull = B_ * H_ + 2 * (S - 1);
      long long sstr = (long long)R * E_;
      for (int l = 0; l < L_; ++l) {
        long long oq = (long long)l * 1536 * 512;
        long long o4 = (long long)l * E_ * E_;
        long long o1 = (long long)l * NHID_ * E_;
        const float* bo_l = bo + l * E_;
        const float* b1_l = b1v + l * NHID_; const float* b2_l = b2v + l * E_;
        const float* g1_l = g1 + l * E_;  const float* be1_l = be1 + l * E_;
        const float* g2_l = g2 + l * E_;  const float* be2_l = be2 + l * E_;

        mgemm(XH, XL, wsu + UQKVH + oq, wsu + UQKVL + oq, BQKV + l * 1536,
              nullptr, QKV, nullptr, nullptr, R, 1536, E_, 0, 1, 0);
        attn_band<<<B_ * 6 * nrb, 256, 0, stream>>>(QKV, XH, XL, S, nrb);
        attn_full<<<nfull, 256, 0, stream>>>(QKV, XH, XL, S);
        attn_unif<<<(B_ - 1) * 2, 256, 0, stream>>>(QKV, XH, XL, S);
        // attn-out: split-2 raw -> SPLIT; ln folds +bo +X residual
        mgemm(XH, XL, wsu + UOH + o4, wsu + UOL + o4, nullptr, nullptr,
              SPLIT, nullptr, nullptr, R, E_, E_, 0, 2, sstr);
        ln_k<<<R, 256, 0, stream>>>(SPLIT, sstr, 2, bo_l, X, 0,
                                    X, g1_l, be1_l, XH, XL, nullptr, nullptr, S);
        mgemm(XH, XL, wsu + U1H + o1, wsu + U1L + o1, b1_l, nullptr, nullptr,
              BIGH, BIGL, R, NHID_, E_, 1 /*relu*/, 1, 0);
        // FFN2: split-4 raw -> SPLIT (spans QKV+TMP); ln folds +b2 +X
        mgemm(BIGH, BIGL, wsu + U2H + o1, wsu + U2L + o1, nullptr, nullptr,
              SPLIT, nullptr, nullptr, R, E_, NHID_, 0, 4, sstr);
        ln_k<<<R, 256, 0, stream>>>(SPLIT, sstr, 4, b2_l, X, 0,
                                    X, g2_l, be2_l, XH, XL, nullptr, nullptr, S);
      }
    };

    auto post = [&](int S, int R){
      long long sstr = (long long)R * E_;
      // fc1: split-2 raw; ln folds +fc1b, gelu, then LN + post scale/bias
      mgemm(XH, XL, wsu + UF1H, wsu + UF1L, nullptr, nullptr,
            SPLIT, nullptr, nullptr, R, E_, E_, 0, 2, sstr);
      ln_k<<<R, 256, 0, stream>>>(SPLIT, sstr, 2, fc1b, nullptr, 2 /*gelu*/,
                                  ALLP, nullptr, nullptr, XH, XL, pscale, pbias, S);
      // fc2: split-2 raw -> FC2S, then add + bias -> PRED
      mgemm(XH, XL, FC2WH, FC2WL, nullptr, nullptr, FC2S,
            nullptr, nullptr, R, 200, E_, 0, 2, (long long)R * 200);
      add_bias2_k<<<(R * 200 + 255) / 256, 256, 0, stream>>>(
          FC2S, FC2S + (long long)R * 200, fc2b, PRED, R * 200, 200);
    };

    // ---------------- pass 1 (S=101) -> outputs 0,1 ----------------
    conv_hl<<<((3232 * 512) + 255) / 256, 256, 0, stream>>>(X1, XH, XL, 3232LL * 512);
    encoder(X1, 101, B_ * 101);
    post(101, B_ * 101);
    copy_cls<<<(B_ * 200 + 255) / 256, 256, 0, stream>>>(PRED, CLS);
    softmax_rows<<<B_, 256, 0, stream>>>(CLS, out + 6400, 200);     // output 1
    softmax_rows<<<200, 256, 0, stream>>>(lab, LSOFT, 200);
    launch_gemm(stream, PRED + 200, fc3w, fc3b, nullptr, TOKMAT, 200, 200, 100,
                1, 200, 100, 1, 200, 0,
                B_, 1, 101LL * 200, 0, 0, 0, 200LL * 200, 0, 1.f, 0);
    tokvec_k<<<B_ * 200, 256, 0, stream>>>(LSOFT, TOKMAT, CLS, TV);
    softmax_rows<<<B_, 256, 0, stream>>>(TV, out, 200);             // output 0

    // ---------------- pass 2 (S=200) -> loss ----------------
    conv_hl<<<((6400 * 512) + 255) / 256, 256, 0, stream>>>(XLN, XH, XL, 6400LL * 512);
    encoder(XLN, SEQ_, B_ * SEQ_);
    post(SEQ_, B_ * SEQ_);
    {
      dim3 g(B_, 4);
      seg_soft_k<<<g, 256, 0, stream>>>(PRED, ALLP, C0p, C1p, A0p, A1p);
    }
    loss_partial_k<<<B_, 256, 0, stream>>>(C0p, C1p, A0p, A1p, PART);
    loss_final_k<<<1, 64, 0, stream>>>(PART, out + 12800);          // output 2
    return;
  }

  // =================== fallback: fp32 path ===================
  const long long O_WCAT = 0;
  const long long O_PROJ = 614400;
  const long long O_FEATS= 8129400;
  const long long O_BIG  = 0;
  const long long O_XLN  = 13107200;
  const long long O_X1   = 16384000;
  const long long O_XQ   = 18038784;
  const long long O_XK   = 21315584;
  const long long O_XV   = 24592384;
  const long long O_CTX  = 27869184;
  const long long O_TMP  = 31145984;
  const long long O_SM   = 34422784;
  const long long O_LSOFT= O_SM;
  const long long O_CLS  = O_LSOFT + 40000;
  const long long O_TV   = O_CLS + 6400;
  const long long O_C0   = O_TV + 6400;
  const long long O_C1   = O_C0 + 6400;
  const long long O_A0   = O_C1 + 6400;
  const long long O_A1   = O_A0 + 16384;
  const long long O_PART = O_A1 + 16384;

  float* WCAT = ws + O_WCAT;
  float* PROJ = ws + O_PROJ;
  float* FEATS= ws + O_FEATS;
  float* BIG  = ws + O_BIG;
  float* XLN  = ws + O_XLN;
  float* X1   = ws + O_X1;
  float* XQ   = ws + O_XQ;
  float* XK   = ws + O_XK;
  float* XV   = ws + O_XV;
  float* CTX  = ws + O_CTX;
  float* TMP  = ws + O_TMP;
  float* LSOFT= ws + O_LSOFT;
  float* CLS  = ws + O_CLS;
  float* TV   = ws + O_TV;
  float* C0p  = ws + O_C0;
  float* C1p  = ws + O_C1;
  float* A0p  = ws + O_A0;
  float* A1p  = ws + O_A1;
  float* PART = ws + O_PART;

  build_wcat<<<(600 * 1024 + 255) / 256, 256, 0, stream>>>(cw1, cw2, cw3, WCAT);
  launch_gemm(stream, emb, WCAT, nullptr, nullptr, PROJ,
              VOC_, 600, TCE_, TCE_, 1, TCE_, 1, 600, 0,
              1, 1, 0,0,0,0,0,0, 1.f, 0);
  feats_k<<<B_ * SEQ_, 320, 0, stream>>>(PROJ, src, cb1, cb2, cb3, FEATS, 600);
  launch_gemm(stream, FEATS, tcfw, tcfb, nullptr, XLN,
              B_ * SEQ_, E_, 300, 300, 1, 300, 1, E_, 0,
              1, 1, 0,0,0,0,0,0, 1.f, 0);
  ln_k<<<B_ * SEQ_, 256, 0, stream>>>(XLN, 0, 1, nullptr, nullptr, 0,
                                      XLN, nullptr, nullptr, nullptr, nullptr,
                                      nullptr, nullptr, SEQ_);
  build_x1<<<(3232 * 512 + 255) / 256, 256, 0, stream>>>(XLN, X1);

  auto encoder = [&](float* X, int S, int R){
    for (int l = 0; l < L_; ++l) {
      const float* Wq_l = Wq + (long long)l * E_ * E_;
      const float* Wk_l = Wk + (long long)l * E_ * E_;
      const float* Wv_l = Wv + (long long)l * E_ * E_;
      const float* Wo_l = Wo + (long long)l * E_ * E_;
      const float* W1_l = W1 + (long long)l * NHID_ * E_;
      const float* W2_l = W2 + (long long)l * E_ * NHID_;
      const float* bq_l = bq + l * E_;  const float* bk_l = bk + l * E_;
      const float* bv_l = bv + l * E_;  const float* bo_l = bo + l * E_;
      const float* b1_l = b1v + l * NHID_; const float* b2_l = b2v + l * E_;
      const float* g1_l = g1 + l * E_;  const float* be1_l = be1 + l * E_;
      const float* g2_l = g2 + l * E_;  const float* be2_l = be2 + l * E_;

      launch_gemm(stream, X, Wq_l, bq_l, nullptr, XQ, R, E_, E_,
                  E_, 1, E_, 1, E_, 0, 1, 1, 0,0,0,0,0,0, 1.f, 0);
      launch_gemm(stream, X, Wk_l, bk_l, nullptr, XK, R, E_, E_,
                  E_, 1, E_, 1, E_, 0, 1, 1, 0,0,0,0,0,0, 1.f, 0);
      launch_gemm(stream, X, Wv_l, bv_l, nullptr, XV, R, E_, E_,
                  E_, 1, E_, 1, E_, 0, 1, 1, 0,0,0,0,0,0, 1.f, 0);
      launch_gemm(stream, XQ, XK, nullptr, nullptr, BIG, S, S, DH_,
                  E_, 1, E_, 1, S, 0,
                  B_ * H_, H_,
                  (long long)S * E_, DH_, (long long)S * E_, DH_,
                  (long long)H_ * S * S, (long long)S * S,
                  0.125f, 0);
      attn_softmax<<<B_ * H_ * S, 256, 0, stream>>>(BIG, S);
      launch_gemm(stream, BIG, XV, nullptr, nullptr, CTX, S, DH_, S,
                  S, 1, 1, E_, E_, 0,
                  B_ * H_, H_,
                  (long long)H_ * S * S, (long long)S * S,
                  (long long)S * E_, DH_,
                  (long long)S * E_, DH_,
                  1.f, 0);
      launch_gemm(stream, CTX, Wo_l, bo_l, X, TMP, R, E_, E_,
                  E_, 1, E_, 1, E_, E_, 1, 1, 0,0,0,0,0,0, 1.f, 0);
      ln_k<<<R, 256, 0, stream>>>(TMP, 0, 1, nullptr, nullptr, 0,
                                  X, g1_l, be1_l, nullptr, nullptr, nullptr, nullptr, S);
      launch_gemm(stream, X, W1_l, b1_l, nullptr, BIG, R, NHID_, E_,
                  E_, 1, E_, 1, NHID_, 0, 1, 1, 0,0,0,0,0,0, 1.f, 1);
      launch_gemm(stream, BIG, W2_l, b2_l, X, TMP, R, E_, NHID_,
                  NHID_, 1, NHID_, 1, E_, E_, 1, 1, 0,0,0,0,0,0, 1.f, 0);
      ln_k<<<R, 256, 0, stream>>>(TMP, 0, 1, nullptr, nullptr, 0,
                                  X, g2_l, be2_l, nullptr, nullptr, nullptr, nullptr, S);
    }
  };

  auto post = [&](float* X, int S, int R, float* H1v, float* ALLPf, float* PREDf){
    launch_gemm(stream, X, fc1w, fc1b, nullptr, H1v, R, E_, E_,
                E_, 1, E_, 1, E_, 0, 1, 1, 0,0,0,0,0,0, 1.f, 2);
    ln_k<<<R, 256, 0, stream>>>(H1v, 0, 1, nullptr, nullptr, 0,
                                ALLPf, nullptr, nullptr, nullptr, nullptr, pscale, pbias, S);
    launch_gemm(stream, ALLPf, fc2w, fc2b, nullptr, PREDf, R, 200, E_,
                E_, 1, E_, 1, 200, 0, 1, 1, 0,0,0,0,0,0, 1.f, 0);
  };

  encoder(X1, 101, B_ * 101);
  post(X1, 101, B_ * 101, XQ, XK, CTX);
  copy_cls<<<(B_ * 200 + 255) / 256, 256, 0, stream>>>(CTX, CLS);
  softmax_rows<<<B_, 256, 0, stream>>>(CLS, out + 6400, 200);
  softmax_rows<<<200, 256, 0, stream>>>(lab, LSOFT, 200);
  launch_gemm(stream, CTX + 200, fc3w, fc3b, nullptr, TMP, 200, 200, 100,
              1, 200, 100, 1, 200, 0,
              B_, 1, 101LL * 200, 0, 0, 0, 200LL * 200, 0, 1.f, 0);
  tokvec_k<<<B_ * 200, 256, 0, stream>>>(LSOFT, TMP, CLS, TV);
  softmax_rows<<<B_, 256, 0, stream>>>(TV, out, 200);

  encoder(XLN, SEQ_, B_ * SEQ_);
  post(XLN, SEQ_, B_ * SEQ_, XQ, XK, CTX);
  {
    dim3 g(B_, 4);
    seg_soft_k<<<g, 256, 0, stream>>>(CTX, XK, C0p, C1p, A0p, A1p);
  }
  loss_partial_k<<<B_, 256, 0, stream>>>(C0p, C1p, A0p, A1p, PART);
  loss_final_k<<<1, 64, 0, stream>>>(PART, out + 12800);
}